// Round 3
// baseline (8214.867 us; speedup 1.0000x reference)
//
#include <hip/hip_runtime.h>
#include <math.h>

constexpr int H    = 500;
constexpr int H3   = 1500;
constexpr int SEQ  = 256;
constexpr int V    = 50257;
constexpr int TDEC = 64;
constexpr int NLT  = (V + 255) / 256;  // probs_k blocks (197)
constexpr int SB   = 50;               // scan blocks per direction
constexpr int UPB  = 10;               // hidden units per scan block
constexpr int NDB  = 256;              // decoder blocks
constexpr int VPB  = (V + NDB - 1) / NDB;  // 197 vocab rows per decoder block

__device__ __forceinline__ float sigmoidf_(float x) { return 1.f / (1.f + expf(-x)); }

__device__ __forceinline__ float wred(float v) {
  #pragma unroll
  for (int off = 32; off > 0; off >>= 1) v += __shfl_down(v, off, 64);
  return v;
}

// Coherent (LLC-routed, L2-bypassing) scalar accesses for cross-block data
// WITHIN a launch. Across launches, plain accesses are safe (end-of-kernel
// release writes back; launch acquire invalidates).
__device__ __forceinline__ float gload(const float* p) {
  return __hip_atomic_load((float*)p, __ATOMIC_RELAXED, __HIP_MEMORY_SCOPE_AGENT);
}
__device__ __forceinline__ void gstore(float* p, float v) {
  __hip_atomic_store(p, v, __ATOMIC_RELAXED, __HIP_MEMORY_SCOPE_AGENT);
}
__device__ __forceinline__ int gload_i(const int* p) {
  return __hip_atomic_load((int*)p, __ATOMIC_RELAXED, __HIP_MEMORY_SCOPE_AGENT);
}
__device__ __forceinline__ void gstore_i(int* p, int v) {
  __hip_atomic_store(p, v, __ATOMIC_RELAXED, __HIP_MEMORY_SCOPE_AGENT);
}

// ---------------- per-block epoch-flag grid sync ----------------
// Producer: drain own sc1 stores (s_waitcnt by every wave, then __syncthreads),
// tid 0 publishes flag[blk]=epoch. Consumers poll all flags in parallel.
__device__ __forceinline__ void flagbar(int* flags, int nblk, int epoch, int blk) {
  __builtin_amdgcn_s_waitcnt(0);   // this wave's sc1 stores are at the LLC
  __syncthreads();                 // all waves of block drained
  if (threadIdx.x == 0) gstore_i(&flags[blk], epoch);
  if ((int)threadIdx.x < nblk)
    while (gload_i(&flags[threadIdx.x]) < epoch) {}
  __syncthreads();
}

// ---------------- init: tok = SOS ----------------
__global__ void init_k(int* tok) {
  if (threadIdx.x == 0) tok[0] = 1;  // SOS
}

// ---------------- embedding lookup: ex[t] = emb[seq[t]] ----------------
__global__ void embed_k(const int* __restrict__ seq, const float* __restrict__ emb,
                        float* __restrict__ ex) {
  int t = blockIdx.x;
  int tok = seq[t];
  for (int i = threadIdx.x; i < H; i += blockDim.x)
    ex[(size_t)t * H + i] = emb[(size_t)tok * H + i];
}

// ---------------- C[m][n] = bias[n] + sum_k X[m*K+k] * W[n*K+k] ----------------
__global__ __launch_bounds__(256) void gemm_nt(const float* __restrict__ X,
                                               const float* __restrict__ W,
                                               const float* __restrict__ bias,
                                               float* __restrict__ C,
                                               int M, int N, int K) {
  __shared__ float Xs[64][17];
  __shared__ float Ws[64][17];
  int bm = blockIdx.y * 64, bn = blockIdx.x * 64;
  int tid = threadIdx.x;
  int tx = tid % 16, ty = tid / 16;
  float acc[4][4] = {};
  for (int k0 = 0; k0 < K; k0 += 16) {
    for (int i = tid; i < 64 * 16; i += 256) {
      int m = i / 16, k = i % 16;
      int gm = bm + m, gk = k0 + k, gn = bn + m;
      Xs[m][k] = (gm < M && gk < K) ? X[(size_t)gm * K + gk] : 0.f;
      Ws[m][k] = (gn < N && gk < K) ? W[(size_t)gn * K + gk] : 0.f;
    }
    __syncthreads();
    #pragma unroll
    for (int k = 0; k < 16; ++k) {
      float xv[4], wv[4];
      #pragma unroll
      for (int i = 0; i < 4; ++i) xv[i] = Xs[ty * 4 + i][k];
      #pragma unroll
      for (int j = 0; j < 4; ++j) wv[j] = Ws[tx * 4 + j][k];
      #pragma unroll
      for (int i = 0; i < 4; ++i)
        #pragma unroll
        for (int j = 0; j < 4; ++j) acc[i][j] += xv[i] * wv[j];
    }
    __syncthreads();
  }
  for (int i = 0; i < 4; ++i) {
    int gm = bm + ty * 4 + i;
    if (gm >= M) continue;
    for (int j = 0; j < 4; ++j) {
      int gn = bn + tx * 4 + j;
      if (gn >= N) continue;
      C[(size_t)gm * N + gn] = acc[i][j] + bias[gn];
    }
  }
}

// ---------------- persistent GRU scan: one launch per layer, fwd+bwd ----------------
__global__ __launch_bounds__(512, 1) void gru_scan_persist(
    const float* __restrict__ gxF, const float* __restrict__ gxB,
    const float* __restrict__ WhhF, const float* __restrict__ WhhB,
    const float* __restrict__ bhhF, const float* __restrict__ bhhB,
    float* __restrict__ hFA, float* __restrict__ hFB,
    float* __restrict__ hBA, float* __restrict__ hBB,
    float* __restrict__ yF, float* __restrict__ yB, int ystride,
    int* flagF, int* flagB) {
  __shared__ float w_lds[30 * 500];   // 60 KB
  __shared__ float gates[32];
  int dir = blockIdx.x / SB;
  int bu  = blockIdx.x % SB;
  int u0  = bu * UPB;
  const float* gx  = dir ? gxB : gxF;
  const float* Whh = dir ? WhhB : WhhF;
  const float* bhh = dir ? bhhB : bhhF;
  float* hA = dir ? hBA : hFA;
  float* hB = dir ? hBB : hFB;
  float* y  = dir ? yB : yF;
  int* flags = dir ? flagB : flagF;
  int tid = threadIdx.x, lane = tid & 63, wid = tid >> 6;

  for (int idx = tid; idx < 30 * 500; idx += 512) {
    int r = idx / 500, k = idx - r * 500;
    int g = r / UPB, lu = r - g * UPB;
    w_lds[idx] = Whh[(size_t)(g * 500 + u0 + lu) * 500 + k];
  }
  int u = u0 + tid;
  float br = 0.f, bz = 0.f, bn = 0.f;
  if (tid < UPB) { br = bhh[u]; bz = bhh[500 + u]; bn = bhh[1000 + u]; }
  __syncthreads();

  float hreg[8];
  for (int t = 0; t < SEQ; ++t) {
    const float* hin  = (t & 1) ? hB : hA;
    float*       hout = (t & 1) ? hA : hB;
    int teff = dir ? (SEQ - 1 - t) : t;
    #pragma unroll
    for (int j = 0; j < 8; ++j) {
      int k = lane + 64 * j;
      hreg[j] = (t > 0 && k < 500) ? gload(&hin[k]) : 0.f;
    }
    float hold = 0.f, gxr = 0.f, gxz = 0.f, gxn = 0.f;
    if (tid < UPB) {
      const float* g = gx + (size_t)teff * H3;
      hold = (t > 0) ? gload(&hin[u]) : 0.f;
      gxr = g[u]; gxz = g[500 + u]; gxn = g[1000 + u];
    }
    for (int r = wid; r < 30; r += 8) {
      const float* wr = &w_lds[r * 500];
      float acc = 0.f;
      #pragma unroll
      for (int j = 0; j < 8; ++j) {
        int k = lane + 64 * j;
        if (k < 500) acc += wr[k] * hreg[j];
      }
      acc = wred(acc);
      if (lane == 0) gates[r] = acc;
    }
    __syncthreads();
    if (tid < UPB) {
      float rr = sigmoidf_(gxr + gates[tid]           + br);
      float zz = sigmoidf_(gxz + gates[UPB + tid]     + bz);
      float nn = tanhf(    gxn + rr * (gates[2 * UPB + tid] + bn));
      float hp = (1.f - zz) * nn + zz * hold;
      gstore(&hout[u], hp);
      y[(size_t)teff * ystride + u] = hp;
    }
    if (t < SEQ - 1) flagbar(flags, SB, t + 1, bu);
  }
}

// ---------------- enc_out = y1f + y1b ----------------
__global__ void add_k(const float* __restrict__ a, const float* __restrict__ b,
                      float* __restrict__ c, int n) {
  int i = blockIdx.x * blockDim.x + threadIdx.x;
  if (i < n) c[i] = a[i] + b[i];
}

// ---------------- per-unit GRU cell (one unit per wave), baseline dot order ----------
__device__ __forceinline__ void cell_unit(int u, int lane, const float* xf, const float* hf,
    const float* __restrict__ Wih, const float* __restrict__ Whh,
    const float* __restrict__ bih, const float* __restrict__ bhh, float* hout) {
  float g[6];
  #pragma unroll
  for (int kind = 0; kind < 6; ++kind) {
    const float* row = (kind < 3) ? (Wih + (size_t)(kind * 500 + u) * 500)
                                  : (Whh + (size_t)((kind - 3) * 500 + u) * 500);
    const float* vec = (kind < 3) ? xf : hf;
    float acc = 0.f;
    #pragma unroll
    for (int j = 0; j < 8; ++j) {
      int k = lane + 64 * j;
      if (k < 500) acc += row[k] * vec[k];
    }
    g[kind] = wred(acc);
  }
  if (lane == 0) {
    float r = sigmoidf_(g[0] + bih[u]        + g[3] + bhh[u]);
    float z = sigmoidf_(g[1] + bih[500 + u]  + g[4] + bhh[500 + u]);
    float n = tanhf(    g[2] + bih[1000 + u] + r * (g[5] + bhh[1000 + u]));
    gstore(&hout[u], (1.f - z) * n + z * hf[u]);
  }
}

// ---------------- whole decoder step in ONE launch (256 blocks x 512) ----------------
// Phases: P(prev probs) A(cell0) B(cell1) C(scores) D(softmax+ctx) E(cvec)
//         F(logits + per-block online-softmax partials) + block0 merge.
// All cross-block data within the launch via sc1; cross-launch via plain.
__global__ __launch_bounds__(512, 1) void dec_step_v3(
    int* __restrict__ tokp, const float* __restrict__ emb,
    const float* __restrict__ h0in, float* __restrict__ h0out,
    const float* __restrict__ h1in, float* __restrict__ h1out,
    const float* __restrict__ dWih, const float* __restrict__ dWhh,
    const float* __restrict__ dbih, const float* __restrict__ dbhh,
    const float* __restrict__ enc_out, const float* __restrict__ cW,
    const float* __restrict__ cb,
    const float* __restrict__ outW, const float* __restrict__ outb,
    float* __restrict__ scores, float* __restrict__ ctx, float* __restrict__ cvec,
    float* __restrict__ logits, float* __restrict__ pm, float* __restrict__ ps,
    int* __restrict__ pix, float* __restrict__ stats,
    float* __restrict__ out_tokens, float* __restrict__ out_probs,
    int* dflags, int st) {
  __shared__ float4 v4[250];           // xh staging: x/rnn [0..500), h/ctx [500..1000)
  __shared__ float red[256], sc[256];
  __shared__ float wm[8], wsum[8]; __shared__ int wix[8];
  __shared__ float mm[256], ms[256]; __shared__ int mi[256];
  float* xf = (float*)v4;
  float* hf = xf + 500;
  int tid = threadIdx.x, lane = tid & 63, wid = tid >> 6, blk = blockIdx.x;
  int ep = st * 6;

  // ---- phase P: write probs of the PREVIOUS step (own v-range; no sync needed) ----
  if (st > 0) {
    float mM = stats[2 * (st - 1)], iS = stats[2 * (st - 1) + 1];
    int base = blk * VPB;
    for (int r = tid; r < VPB; r += 512) {
      int v = base + r;
      if (v < V) out_probs[(size_t)(st - 1) * V + v] = expf(logits[v] - mM) * iS;
    }
  }

  // ---- phase A: layer-0 GRU cell, unit-per-wave on blocks 0..62 ----
  int u = blk * 8 + wid;
  if (blk < 63) {
    int tk = tokp[0];                      // plain: written by prev launch
    for (int i = tid; i < 500; i += 512) {
      xf[i] = emb[(size_t)tk * 500 + i];
      hf[i] = h0in[i];                     // plain: prev launch / encoder
    }
    __syncthreads();
    if (u < 500) cell_unit(u, lane, xf, hf, dWih, dWhh, dbih, dbhh, h0out);
  }
  flagbar(dflags, NDB, ep + 1, blk);

  // ---- phase B: layer-1 GRU cell (x = h0out) ----
  if (blk < 63) {
    for (int i = tid; i < 500; i += 512) {
      xf[i] = gload(&h0out[i]);
      hf[i] = h1in[i];
    }
    __syncthreads();
    if (u < 500) cell_unit(u, lane, xf, hf,
        dWih + 750000, dWhh + 750000, dbih + 1500, dbhh + 1500, h1out);
  }
  flagbar(dflags, NDB, ep + 2, blk);

  // ---- phase C: attention scores, score-per-wave on blocks 0..31 ----
  if (blk < 32) {
    for (int i = tid; i < 500; i += 512) xf[i] = gload(&h1out[i]);
    __syncthreads();
    int s = blk * 8 + wid;
    const float* row = enc_out + (size_t)s * 500;
    float acc = 0.f;
    #pragma unroll
    for (int j = 0; j < 8; ++j) {
      int k = lane + 64 * j;
      if (k < 500) acc += row[k] * xf[k];
    }
    acc = wred(acc);
    if (lane == 0) gstore(&scores[s], acc);
  }
  flagbar(dflags, NDB, ep + 3, blk);

  // ---- phase D: softmax (blocks 0..62, locally) + ctx col-per-wave ----
  if (blk < 63) {
    float myv = 0.f;
    if (tid < 256) { myv = gload(&scores[tid]); red[tid] = myv; }
    __syncthreads();
    for (int s = 128; s > 0; s >>= 1) {
      if (tid < s) red[tid] = fmaxf(red[tid], red[tid + s]);
      __syncthreads();
    }
    float m = red[0]; __syncthreads();
    float e = 0.f;
    if (tid < 256) { e = expf(myv - m); red[tid] = e; }
    __syncthreads();
    for (int s = 128; s > 0; s >>= 1) {
      if (tid < s) red[tid] += red[tid + s];
      __syncthreads();
    }
    float inv = 1.f / red[0]; __syncthreads();
    if (tid < 256) sc[tid] = e * inv;
    __syncthreads();
    int j = blk * 8 + wid;
    if (j < 500) {
      float acc = 0.f;
      #pragma unroll
      for (int q = 0; q < 4; ++q) {
        int s = lane + 64 * q;
        acc += sc[s] * enc_out[(size_t)s * 500 + j];
      }
      acc = wred(acc);
      if (lane == 0) gstore(&ctx[j], acc);
    }
  }
  flagbar(dflags, NDB, ep + 4, blk);

  // ---- phase E: cvec row-per-wave on blocks 0..62 ----
  if (blk < 63) {
    for (int i = tid; i < 500; i += 512) {
      xf[i] = gload(&h1out[i]);   // rnn
      hf[i] = gload(&ctx[i]);     // ctx (xf[500+i])
    }
    __syncthreads();
    int i = blk * 8 + wid;
    if (i < 500) {
      const float* row = cW + (size_t)i * 1000;
      float acc = 0.f;
      #pragma unroll
      for (int j = 0; j < 16; ++j) {
        int k = lane + 64 * j;
        if (k < 1000) acc += row[k] * xf[k];
      }
      acc = wred(acc);
      if (lane == 0) gstore(&cvec[i], tanhf(acc + cb[i]));
    }
  }
  flagbar(dflags, NDB, ep + 5, blk);

  // ---- phase F: logits rows [blk*VPB, blk*VPB+VPB), online max/sum/argmax ----
  for (int i = tid; i < 500; i += 512) xf[i] = gload(&cvec[i]);
  __syncthreads();
  const float4* c4 = v4;
  {
    int lstart = wid * 25, lend = (wid + 1) * 25; if (lend > VPB) lend = VPB;
    int r0 = blk * VPB + lstart, r1 = blk * VPB + lend; if (r1 > V) r1 = V;
    float m = -1e30f, ssum = 0.f; int ix = V;
    for (int row = r0; row < r1; ++row) {
      const float4* wrow = (const float4*)(outW + (size_t)row * 500);
      float acc = 0.f;
      #pragma unroll
      for (int q = 0; q < 2; ++q) {
        int k4 = lane + 64 * q;
        if (k4 < 125) {
          float4 w4 = wrow[k4]; float4 cc = c4[k4];
          acc += w4.x * cc.x + w4.y * cc.y + w4.z * cc.z + w4.w * cc.w;
        }
      }
      acc = wred(acc);
      if (lane == 0) {
        float l = acc + outb[row];
        logits[row] = l;          // plain: read by next launch (phase P)
        if (l > m) { ssum = ssum * expf(m - l) + 1.f; m = l; ix = row; }
        else       { ssum += expf(l - m); }
      }
    }
    if (lane == 0) { wm[wid] = m; wsum[wid] = ssum; wix[wid] = ix; }
  }
  __syncthreads();
  if (tid == 0) {
    float M = wm[0], S = wsum[0]; int I = wix[0];
    for (int w = 1; w < 8; ++w) {
      if (wm[w] > M) { S = S * expf(M - wm[w]) + wsum[w]; M = wm[w]; I = wix[w]; }
      else           { S += wsum[w] * expf(wm[w] - M); }
    }
    gstore(&pm[blk], M); gstore(&ps[blk], S); gstore_i(&pix[blk], I);
  }
  flagbar(dflags, NDB, ep + 6, blk);

  // ---- block 0: global merge -> token, stats ----
  if (blk == 0) {
    if (tid < 256) { mm[tid] = gload(&pm[tid]); ms[tid] = gload(&ps[tid]); mi[tid] = gload_i(&pix[tid]); }
    __syncthreads();
    for (int s = 128; s > 0; s >>= 1) {
      if (tid < s) {
        float ma = mm[tid], mb = mm[tid + s];
        float sa = ms[tid], sb = ms[tid + s];
        int ia = mi[tid], ib = mi[tid + s];
        if (mb > ma || (mb == ma && ib < ia)) {
          ms[tid] = sa * expf(ma - mb) + sb; mm[tid] = mb; mi[tid] = ib;
        } else {
          ms[tid] = sa + sb * expf(mb - ma);
        }
      }
      __syncthreads();
    }
    if (tid == 0) {
      tokp[0] = mi[0];                    // plain: next launch
      out_tokens[st] = (float)mi[0];
      stats[2 * st] = mm[0];
      stats[2 * st + 1] = 1.f / ms[0];
    }
  }
}

// ---------------- wide probs write for the final step ----------------
__global__ __launch_bounds__(256) void probs_k(const float* __restrict__ logits,
    const float* __restrict__ stats, float* __restrict__ out_probs) {
  int v = blockIdx.x * 256 + threadIdx.x;
  if (v < V) out_probs[v] = expf(logits[v] - stats[0]) * stats[1];
}

extern "C" void kernel_launch(void* const* d_in, const int* in_sizes, int n_in,
                              void* d_out, int out_size, void* d_ws, size_t ws_size,
                              hipStream_t stream) {
  const int*   seq   = (const int*)d_in[0];
  const float* emb   = (const float*)d_in[3];
  const float* e0f_Wih = (const float*)d_in[4];
  const float* e0f_Whh = (const float*)d_in[5];
  const float* e0f_bih = (const float*)d_in[6];
  const float* e0f_bhh = (const float*)d_in[7];
  const float* e0b_Wih = (const float*)d_in[8];
  const float* e0b_Whh = (const float*)d_in[9];
  const float* e0b_bih = (const float*)d_in[10];
  const float* e0b_bhh = (const float*)d_in[11];
  const float* e1f_Wih = (const float*)d_in[12];
  const float* e1f_Whh = (const float*)d_in[13];
  const float* e1f_bih = (const float*)d_in[14];
  const float* e1f_bhh = (const float*)d_in[15];
  const float* e1b_Wih = (const float*)d_in[16];
  const float* e1b_Whh = (const float*)d_in[17];
  const float* e1b_bih = (const float*)d_in[18];
  const float* e1b_bhh = (const float*)d_in[19];
  const float* dWih = (const float*)d_in[20];
  const float* dWhh = (const float*)d_in[21];
  const float* dbih = (const float*)d_in[22];
  const float* dbhh = (const float*)d_in[23];
  const float* cW   = (const float*)d_in[24];
  const float* cb   = (const float*)d_in[25];
  const float* outW = (const float*)d_in[26];
  const float* outb = (const float*)d_in[27];

  float* w = (float*)d_ws;
  float* ex      = w;                      // 128000
  float* x1      = ex + 128000;            // 256000
  float* gxf     = x1 + 256000;            // 384000
  float* gxb     = gxf + 384000;           // 384000
  float* y1f     = gxb + 384000;           // 128000
  float* y1b     = y1f + 128000;           // 128000
  float* enc_out = y1b + 128000;           // 128000
  float* hb      = enc_out + 128000;       // 8 x 512 h ping-pong buffers
  float* hL0FA = hb;          float* hL0FB = hb + 512;
  float* hL0BA = hb + 1024;   float* hL0BB = hb + 1536;
  float* hL1FA = hb + 2048;   float* hL1FB = hb + 2560;
  float* hL1BA = hb + 3072;   float* hL1BB = hb + 3584;
  float* dsc0   = hb + 4096;               // 512
  float* dsc1   = dsc0 + 512;              // 512
  float* scores = dsc1 + 512;              // 512
  float* ctx    = scores + 512;            // 512
  float* cvec   = ctx + 512;               // 512
  float* logits = cvec + 512;              // 50432
  float* pm     = logits + 50432;          // 256
  float* ps     = pm + 256;                // 256
  float* stats  = ps + 256;                // 192 (2 per step)
  int*   pix    = (int*)(stats + 192);     // 256 ints
  int*   tokp   = pix + 256;               // 64 ints
  int*   bar    = tokp + 64;               // 512 ints: scan flags (4x64) + dec flags (256)

  float* outf = (float*)d_out;

  // zero all sync flags (d_ws is re-poisoned before every call)
  hipMemsetAsync(bar, 0, 512 * sizeof(int), stream);

  init_k<<<1, 64, 0, stream>>>(tokp);
  embed_k<<<SEQ, 128, 0, stream>>>(seq, emb, ex);

  // encoder layer 0
  gemm_nt<<<dim3(24, 4), 256, 0, stream>>>(ex, e0f_Wih, e0f_bih, gxf, SEQ, H3, H);
  gemm_nt<<<dim3(24, 4), 256, 0, stream>>>(ex, e0b_Wih, e0b_bih, gxb, SEQ, H3, H);
  gru_scan_persist<<<2 * SB, 512, 0, stream>>>(gxf, gxb, e0f_Whh, e0b_Whh,
      e0f_bhh, e0b_bhh, hL0FA, hL0FB, hL0BA, hL0BB, x1, x1 + 500, 1000,
      bar + 0, bar + 64);

  // encoder layer 1
  gemm_nt<<<dim3(24, 4), 256, 0, stream>>>(x1, e1f_Wih, e1f_bih, gxf, SEQ, H3, 2 * H);
  gemm_nt<<<dim3(24, 4), 256, 0, stream>>>(x1, e1b_Wih, e1b_bih, gxb, SEQ, H3, 2 * H);
  gru_scan_persist<<<2 * SB, 512, 0, stream>>>(gxf, gxb, e1f_Whh, e1b_Whh,
      e1f_bhh, e1b_bhh, hL1FA, hL1FB, hL1BA, hL1BB, y1f, y1b, 500,
      bar + 128, bar + 192);
  add_k<<<(SEQ * H + 255) / 256, 256, 0, stream>>>(y1f, y1b, enc_out, SEQ * H);

  // decoder: one launch per step; probs of step st written during step st+1
  float* h0c = hL0FA; float* h0a = dsc0;
  float* h1c = hL0BA; float* h1a = dsc1;
  for (int st = 0; st < TDEC; ++st) {
    dec_step_v3<<<NDB, 512, 0, stream>>>(tokp, emb, h0c, h0a, h1c, h1a,
        dWih, dWhh, dbih, dbhh, enc_out, cW, cb, outW, outb,
        scores, ctx, cvec, logits, pm, ps, pix, stats,
        outf, outf + TDEC, bar + 256, st);
    float* t0 = h0c; h0c = h0a; h0a = t0;
    float* t1 = h1c; h1c = h1a; h1a = t1;
  }
  probs_k<<<NLT, 256, 0, stream>>>(logits, stats + 2 * (TDEC - 1),
      outf + TDEC + (size_t)(TDEC - 1) * V);
}

// Round 4
// 6869.191 us; speedup vs baseline: 1.1959x; 1.1959x over previous
//
#include <hip/hip_runtime.h>
#include <math.h>

typedef unsigned long long ull;

constexpr int H    = 500;
constexpr int H3   = 1500;
constexpr int SEQ  = 256;
constexpr int V    = 50257;
constexpr int TDEC = 64;
constexpr int NLT  = (V + 255) / 256;  // probs_k blocks (197)
constexpr int SB   = 50;               // scan blocks per direction
constexpr int UPB  = 10;               // hidden units per scan block
constexpr int NDB  = 256;              // decoder blocks
constexpr int VPB  = (V + NDB - 1) / NDB;  // 197 vocab rows per decoder block

__device__ __forceinline__ float sigmoidf_(float x) { return 1.f / (1.f + expf(-x)); }

__device__ __forceinline__ float wred(float v) {
  #pragma unroll
  for (int off = 32; off > 0; off >>= 1) v += __shfl_down(v, off, 64);
  return v;
}

// Coherent (LLC-routed, L2-bypassing) scalar accesses for cross-block data
// WITHIN a launch. Across launches, plain accesses are safe.
__device__ __forceinline__ float gload(const float* p) {
  return __hip_atomic_load((float*)p, __ATOMIC_RELAXED, __HIP_MEMORY_SCOPE_AGENT);
}
__device__ __forceinline__ void gstore(float* p, float v) {
  __hip_atomic_store(p, v, __ATOMIC_RELAXED, __HIP_MEMORY_SCOPE_AGENT);
}
__device__ __forceinline__ int gload_i(const int* p) {
  return __hip_atomic_load((int*)p, __ATOMIC_RELAXED, __HIP_MEMORY_SCOPE_AGENT);
}
__device__ __forceinline__ void gstore_i(int* p, int v) {
  __hip_atomic_store(p, v, __ATOMIC_RELAXED, __HIP_MEMORY_SCOPE_AGENT);
}
__device__ __forceinline__ ull gload64(const ull* p) {
  return __hip_atomic_load((ull*)p, __ATOMIC_RELAXED, __HIP_MEMORY_SCOPE_AGENT);
}
__device__ __forceinline__ void gstore64(ull* p, ull v) {
  __hip_atomic_store(p, v, __ATOMIC_RELAXED, __HIP_MEMORY_SCOPE_AGENT);
}

// ---------------- per-block epoch-flag grid sync (small groups) ----------------
__device__ __forceinline__ void flagbar(int* flags, int nblk, int epoch, int blk) {
  __builtin_amdgcn_s_waitcnt(0);   // this wave's sc1 stores are at the LLC
  __syncthreads();                 // all waves of block drained
  if (threadIdx.x == 0) gstore_i(&flags[blk], epoch);
  if ((int)threadIdx.x < nblk)
    while (gload_i(&flags[threadIdx.x]) < epoch) {}
  __syncthreads();
}

// ---------------- init: tok = SOS ----------------
__global__ void init_k(int* tok) {
  if (threadIdx.x == 0) tok[0] = 1;  // SOS
}

// ---------------- embedding lookup: ex[t] = emb[seq[t]] ----------------
__global__ void embed_k(const int* __restrict__ seq, const float* __restrict__ emb,
                        float* __restrict__ ex) {
  int t = blockIdx.x;
  int tok = seq[t];
  for (int i = threadIdx.x; i < H; i += blockDim.x)
    ex[(size_t)t * H + i] = emb[(size_t)tok * H + i];
}

// ---------------- C[m][n] = bias[n] + sum_k X[m*K+k] * W[n*K+k] ----------------
__global__ __launch_bounds__(256) void gemm_nt(const float* __restrict__ X,
                                               const float* __restrict__ W,
                                               const float* __restrict__ bias,
                                               float* __restrict__ C,
                                               int M, int N, int K) {
  __shared__ float Xs[64][17];
  __shared__ float Ws[64][17];
  int bm = blockIdx.y * 64, bn = blockIdx.x * 64;
  int tid = threadIdx.x;
  int tx = tid % 16, ty = tid / 16;
  float acc[4][4] = {};
  for (int k0 = 0; k0 < K; k0 += 16) {
    for (int i = tid; i < 64 * 16; i += 256) {
      int m = i / 16, k = i % 16;
      int gm = bm + m, gk = k0 + k, gn = bn + m;
      Xs[m][k] = (gm < M && gk < K) ? X[(size_t)gm * K + gk] : 0.f;
      Ws[m][k] = (gn < N && gk < K) ? W[(size_t)gn * K + gk] : 0.f;
    }
    __syncthreads();
    #pragma unroll
    for (int k = 0; k < 16; ++k) {
      float xv[4], wv[4];
      #pragma unroll
      for (int i = 0; i < 4; ++i) xv[i] = Xs[ty * 4 + i][k];
      #pragma unroll
      for (int j = 0; j < 4; ++j) wv[j] = Ws[tx * 4 + j][k];
      #pragma unroll
      for (int i = 0; i < 4; ++i)
        #pragma unroll
        for (int j = 0; j < 4; ++j) acc[i][j] += xv[i] * wv[j];
    }
    __syncthreads();
  }
  for (int i = 0; i < 4; ++i) {
    int gm = bm + ty * 4 + i;
    if (gm >= M) continue;
    for (int j = 0; j < 4; ++j) {
      int gn = bn + tx * 4 + j;
      if (gn >= N) continue;
      C[(size_t)gm * N + gn] = acc[i][j] + bias[gn];
    }
  }
}

// ---------------- persistent GRU scan with TAGGED-H sync ----------------
// Each h unit is published as a 64-bit word {tag = t+1 (hi), float bits (lo)}
// via one 8B agent-scope atomic. Consumers (wave 0 of each block) poll the
// tagged words directly: data arrival IS the sync. No barriers in the loop.
// WAR safety on the ping-pong: a block reaches step t only after seeing all
// tags==t, which requires every block to have finished its step-(t-1) poll of
// the buffer this step overwrites (poll loads complete before the dependent
// tag store issues).
__global__ __launch_bounds__(512, 1) void gru_scan_tag(
    const float* __restrict__ gxF, const float* __restrict__ gxB,
    const float* __restrict__ WhhF, const float* __restrict__ WhhB,
    const float* __restrict__ bhhF, const float* __restrict__ bhhB,
    ull* __restrict__ tAF, ull* __restrict__ tBF,
    ull* __restrict__ tAB, ull* __restrict__ tBB,
    float* __restrict__ yF, float* __restrict__ yB, int ystride) {
  __shared__ float w_lds[30 * 500];   // 60 KB
  __shared__ float gates[32];
  __shared__ float h_lds[512];
  int dir = blockIdx.x / SB;
  int bu  = blockIdx.x % SB;
  int u0  = bu * UPB;
  const float* gx  = dir ? gxB : gxF;
  const float* Whh = dir ? WhhB : WhhF;
  const float* bhh = dir ? bhhB : bhhF;
  ull* tagA = dir ? tAB : tAF;
  ull* tagB = dir ? tBB : tBF;
  float* y  = dir ? yB : yF;
  int tid = threadIdx.x, lane = tid & 63, wid = tid >> 6;

  for (int idx = tid; idx < 30 * 500; idx += 512) {
    int r = idx / 500, k = idx - r * 500;
    int g = r / UPB, lu = r - g * UPB;
    w_lds[idx] = Whh[(size_t)(g * 500 + u0 + lu) * 500 + k];
  }
  int u = u0 + tid;
  float br = 0.f, bz = 0.f, bn = 0.f;
  if (tid < UPB) { br = bhh[u]; bz = bhh[500 + u]; bn = bhh[1000 + u]; }
  h_lds[tid] = 0.f;
  __syncthreads();

  for (int t = 0; t < SEQ; ++t) {
    // step t writes W(t) = (t&1)?A:B ; reads W(t-1) = (t&1)?B:A
    ull* wout = (t & 1) ? tagA : tagB;
    ull* win  = (t & 1) ? tagB : tagA;
    int teff = dir ? (SEQ - 1 - t) : t;

    // issue gate-input loads early (independent of h)
    float gxr = 0.f, gxz = 0.f, gxn = 0.f;
    if (tid < UPB) {
      const float* g = gx + (size_t)teff * H3;
      gxr = g[u]; gxz = g[500 + u]; gxn = g[1000 + u];
    }

    if (t > 0 && wid == 0) {
      ull v[8];
      for (;;) {
        bool ok = true;
        #pragma unroll
        for (int j = 0; j < 8; ++j) {
          int k = lane + 64 * j;
          if (k < 500) {
            v[j] = gload64(&win[k]);
            if ((unsigned)(v[j] >> 32) != (unsigned)t) ok = false;
          }
        }
        if (ok) break;
        __builtin_amdgcn_s_sleep(1);
      }
      #pragma unroll
      for (int j = 0; j < 8; ++j) {
        int k = lane + 64 * j;
        if (k < 500) h_lds[k] = __uint_as_float((unsigned)v[j]);
      }
    }
    __syncthreads();

    float hreg[8];
    #pragma unroll
    for (int j = 0; j < 8; ++j) {
      int k = lane + 64 * j;
      hreg[j] = (k < 500) ? h_lds[k] : 0.f;
    }
    for (int r = wid; r < 30; r += 8) {
      const float* wr = &w_lds[r * 500];
      float acc = 0.f;
      #pragma unroll
      for (int j = 0; j < 8; ++j) {
        int k = lane + 64 * j;
        if (k < 500) acc += wr[k] * hreg[j];
      }
      acc = wred(acc);
      if (lane == 0) gates[r] = acc;
    }
    __syncthreads();
    if (tid < UPB) {
      float hold = h_lds[u];
      float rr = sigmoidf_(gxr + gates[tid]           + br);
      float zz = sigmoidf_(gxz + gates[UPB + tid]     + bz);
      float nn = tanhf(    gxn + rr * (gates[2 * UPB + tid] + bn));
      float hp = (1.f - zz) * nn + zz * hold;
      ull pv = ((ull)(unsigned)(t + 1) << 32) | (ull)__float_as_uint(hp);
      gstore64(&wout[u], pv);
      y[(size_t)teff * ystride + u] = hp;
    }
    // no barrier: next iteration's poll (wave 0) is the sync; waves 1-7 wait
    // at the next __syncthreads, which is after their h_lds reads completed.
  }
}

// ---------------- unpack final layer-0 hidden states for the decoder ----------------
__global__ void unpack_k(const ull* __restrict__ ta, const ull* __restrict__ tb,
                         float* __restrict__ ha, float* __restrict__ hb_) {
  int i = threadIdx.x;
  if (i < 500) {
    ha[i]  = __uint_as_float((unsigned)ta[i]);
    hb_[i] = __uint_as_float((unsigned)tb[i]);
  }
}

// ---------------- enc_out = y1f + y1b ----------------
__global__ void add_k(const float* __restrict__ a, const float* __restrict__ b,
                      float* __restrict__ c, int n) {
  int i = blockIdx.x * blockDim.x + threadIdx.x;
  if (i < n) c[i] = a[i] + b[i];
}

// ---------------- per-unit GRU cell (one unit per wave), baseline dot order ----------
__device__ __forceinline__ void cell_unit(int u, int lane, const float* xf, const float* hf,
    const float* __restrict__ Wih, const float* __restrict__ Whh,
    const float* __restrict__ bih, const float* __restrict__ bhh, float* hout) {
  float g[6];
  #pragma unroll
  for (int kind = 0; kind < 6; ++kind) {
    const float* row = (kind < 3) ? (Wih + (size_t)(kind * 500 + u) * 500)
                                  : (Whh + (size_t)((kind - 3) * 500 + u) * 500);
    const float* vec = (kind < 3) ? xf : hf;
    float acc = 0.f;
    #pragma unroll
    for (int j = 0; j < 8; ++j) {
      int k = lane + 64 * j;
      if (k < 500) acc += row[k] * vec[k];
    }
    g[kind] = wred(acc);
  }
  if (lane == 0) {
    float r = sigmoidf_(g[0] + bih[u]        + g[3] + bhh[u]);
    float z = sigmoidf_(g[1] + bih[500 + u]  + g[4] + bhh[500 + u]);
    float n = tanhf(    g[2] + bih[1000 + u] + r * (g[5] + bhh[1000 + u]));
    gstore(&hout[u], (1.f - z) * n + z * hf[u]);
  }
}

// ---------------- whole decoder step in ONE launch (256 blocks x 512) ----------------
// P: all blocks write prev-step probs (own rows; block-private -> no sync).
// A..E: blocks 0..62 (4 small flagbars among 63 blocks).
// join: workers publish ep+5; everyone sleep-polls it.
// F: all 256 blocks compute logits rows + online-softmax partials.
// merge: last block to finish (atomic done-counter) merges partials -> token/stats.
__global__ __launch_bounds__(512, 1) void dec_step_v4(
    int* __restrict__ tokp, const float* __restrict__ emb,
    const float* __restrict__ h0in, float* __restrict__ h0out,
    const float* __restrict__ h1in, float* __restrict__ h1out,
    const float* __restrict__ dWih, const float* __restrict__ dWhh,
    const float* __restrict__ dbih, const float* __restrict__ dbhh,
    const float* __restrict__ enc_out, const float* __restrict__ cW,
    const float* __restrict__ cb,
    const float* __restrict__ outW, const float* __restrict__ outb,
    float* __restrict__ scores, float* __restrict__ ctx, float* __restrict__ cvec,
    float* __restrict__ logits, float* __restrict__ pm, float* __restrict__ ps,
    int* __restrict__ pix, float* __restrict__ stats,
    float* __restrict__ out_tokens, float* __restrict__ out_probs,
    int* dflags, int* dcnt, int st) {
  __shared__ float4 v4[250];           // xf [0..500), hf [500..1000)
  __shared__ float red[256], sc[256];
  __shared__ float wm[8], wsum[8]; __shared__ int wix[8];
  __shared__ float mm[256], ms[256]; __shared__ int mi[256];
  __shared__ int lastf;
  float* xf = (float*)v4;
  float* hf = xf + 500;
  int tid = threadIdx.x, lane = tid & 63, wid = tid >> 6, blk = blockIdx.x;
  int ep = st * 5;

  // ---- phase P: probs of the PREVIOUS step (block-private rows) ----
  if (st > 0) {
    float mM = stats[2 * (st - 1)], iS = stats[2 * (st - 1) + 1];
    int base = blk * VPB;
    for (int r = tid; r < VPB; r += 512) {
      int v = base + r;
      if (v < V) out_probs[(size_t)(st - 1) * V + v] = expf(logits[v] - mM) * iS;
    }
  }

  if (blk < 63) {
    int u = blk * 8 + wid;
    // ---- A: layer-0 cell ----
    int tk = tokp[0];
    for (int i = tid; i < 500; i += 512) {
      xf[i] = emb[(size_t)tk * 500 + i];
      hf[i] = h0in[i];
    }
    __syncthreads();
    if (u < 500) cell_unit(u, lane, xf, hf, dWih, dWhh, dbih, dbhh, h0out);
    flagbar(dflags, 63, ep + 1, blk);

    // ---- B: layer-1 cell ----
    for (int i = tid; i < 500; i += 512) {
      xf[i] = gload(&h0out[i]);
      hf[i] = h1in[i];
    }
    __syncthreads();
    if (u < 500) cell_unit(u, lane, xf, hf,
        dWih + 750000, dWhh + 750000, dbih + 1500, dbhh + 1500, h1out);
    flagbar(dflags, 63, ep + 2, blk);

    // ---- C: attention scores (blocks 0..31, 8 scores each) ----
    for (int i = tid; i < 500; i += 512) xf[i] = gload(&h1out[i]);
    __syncthreads();
    if (blk < 32) {
      int s = blk * 8 + wid;
      const float* row = enc_out + (size_t)s * 500;
      float acc = 0.f;
      #pragma unroll
      for (int j = 0; j < 8; ++j) {
        int k = lane + 64 * j;
        if (k < 500) acc += row[k] * xf[k];
      }
      acc = wred(acc);
      if (lane == 0) gstore(&scores[s], acc);
    }
    flagbar(dflags, 63, ep + 3, blk);

    // ---- D: softmax (local) + ctx (8 cols/block) ----
    {
      float myv = 0.f;
      if (tid < 256) { myv = gload(&scores[tid]); red[tid] = myv; }
      __syncthreads();
      for (int s = 128; s > 0; s >>= 1) {
        if (tid < s) red[tid] = fmaxf(red[tid], red[tid + s]);
        __syncthreads();
      }
      float m = red[0]; __syncthreads();
      float e = 0.f;
      if (tid < 256) { e = expf(myv - m); red[tid] = e; }
      __syncthreads();
      for (int s = 128; s > 0; s >>= 1) {
        if (tid < s) red[tid] += red[tid + s];
        __syncthreads();
      }
      float inv = 1.f / red[0]; __syncthreads();
      if (tid < 256) sc[tid] = e * inv;
      __syncthreads();
      int j = blk * 8 + wid;
      if (j < 500) {
        float acc = 0.f;
        #pragma unroll
        for (int q = 0; q < 4; ++q) {
          int s = lane + 64 * q;
          acc += sc[s] * enc_out[(size_t)s * 500 + j];
        }
        acc = wred(acc);
        if (lane == 0) gstore(&ctx[j], acc);
      }
    }
    flagbar(dflags, 63, ep + 4, blk);

    // ---- E: cvec (8 rows/block) ----
    for (int i = tid; i < 500; i += 512) {
      xf[i] = gload(&h1out[i]);   // rnn
      hf[i] = gload(&ctx[i]);     // ctx at xf[500+i]
    }
    __syncthreads();
    {
      int i = blk * 8 + wid;
      if (i < 500) {
        const float* row = cW + (size_t)i * 1000;
        float acc = 0.f;
        #pragma unroll
        for (int j = 0; j < 16; ++j) {
          int k = lane + 64 * j;
          if (k < 1000) acc += row[k] * xf[k];
        }
        acc = wred(acc);
        if (lane == 0) gstore(&cvec[i], tanhf(acc + cb[i]));
      }
    }
  }

  // ---- join: workers publish ep+5; everyone waits for all 63 ----
  __builtin_amdgcn_s_waitcnt(0);
  __syncthreads();
  if (blk < 63 && tid == 0) gstore_i(&dflags[blk], ep + 5);
  if (tid < 63) {
    while (gload_i(&dflags[tid]) < ep + 5) __builtin_amdgcn_s_sleep(2);
  }
  __syncthreads();

  // ---- F: logits rows [blk*VPB, ...), 4-row batches for MLP ----
  for (int i = tid; i < 500; i += 512) xf[i] = gload(&cvec[i]);
  __syncthreads();
  const float4* c4 = v4;
  {
    int lstart = wid * 25, lend = (wid + 1) * 25; if (lend > VPB) lend = VPB;
    int r0 = blk * VPB + lstart, r1 = blk * VPB + lend; if (r1 > V) r1 = V;
    float m = -1e30f, ssum = 0.f; int ix = V;
    for (int rb = r0; rb < r1; rb += 4) {
      int nr = r1 - rb; if (nr > 4) nr = 4;
      float a[4] = {0.f, 0.f, 0.f, 0.f};
      #pragma unroll
      for (int q = 0; q < 2; ++q) {
        int k4 = lane + 64 * q;
        if (k4 < 125) {
          float4 cc = c4[k4];
          #pragma unroll
          for (int rr = 0; rr < 4; ++rr) {
            if (rr < nr) {
              float4 w4 = ((const float4*)(outW + (size_t)(rb + rr) * 500))[k4];
              a[rr] += w4.x * cc.x + w4.y * cc.y + w4.z * cc.z + w4.w * cc.w;
            }
          }
        }
      }
      #pragma unroll
      for (int rr = 0; rr < 4; ++rr) {
        if (rr < nr) {
          float l = wred(a[rr]);
          if (lane == 0) {
            l += outb[rb + rr];
            logits[rb + rr] = l;   // plain: next launch (phase P) reads
            if (l > m) { ssum = ssum * expf(m - l) + 1.f; m = l; ix = rb + rr; }
            else       { ssum += expf(l - m); }
          }
        }
      }
    }
    if (lane == 0) { wm[wid] = m; wsum[wid] = ssum; wix[wid] = ix; }
  }
  __syncthreads();
  if (tid == 0) {
    float M = wm[0], S = wsum[0]; int I = wix[0];
    for (int w = 1; w < 8; ++w) {
      if (wm[w] > M) { S = S * expf(M - wm[w]) + wsum[w]; M = wm[w]; I = wix[w]; }
      else           { S += wsum[w] * expf(wm[w] - M); }
    }
    gstore(&pm[blk], M); gstore(&ps[blk], S); gstore_i(&pix[blk], I);
    __builtin_amdgcn_s_waitcnt(0);   // partials at LLC before the increment
    int prev = __hip_atomic_fetch_add(&dcnt[st], 1, __ATOMIC_RELAXED,
                                      __HIP_MEMORY_SCOPE_AGENT);
    lastf = (prev == NDB - 1) ? 1 : 0;
  }
  __syncthreads();

  // ---- last block merges the 256 partials -> token, stats ----
  if (lastf) {
    if (tid < 256) { mm[tid] = gload(&pm[tid]); ms[tid] = gload(&ps[tid]); mi[tid] = gload_i(&pix[tid]); }
    __syncthreads();
    for (int s = 128; s > 0; s >>= 1) {
      if (tid < s) {
        float ma = mm[tid], mb = mm[tid + s];
        float sa = ms[tid], sb = ms[tid + s];
        int ia = mi[tid], ib = mi[tid + s];
        if (mb > ma || (mb == ma && ib < ia)) {
          ms[tid] = sa * expf(ma - mb) + sb; mm[tid] = mb; mi[tid] = ib;
        } else {
          ms[tid] = sa + sb * expf(mb - ma);
        }
      }
      __syncthreads();
    }
    if (tid == 0) {
      tokp[0] = mi[0];
      out_tokens[st] = (float)mi[0];
      stats[2 * st] = mm[0];
      stats[2 * st + 1] = 1.f / ms[0];
    }
  }
}

// ---------------- wide probs write for the final step ----------------
__global__ __launch_bounds__(256) void probs_k(const float* __restrict__ logits,
    const float* __restrict__ stats, float* __restrict__ out_probs) {
  int v = blockIdx.x * 256 + threadIdx.x;
  if (v < V) out_probs[v] = expf(logits[v] - stats[0]) * stats[1];
}

extern "C" void kernel_launch(void* const* d_in, const int* in_sizes, int n_in,
                              void* d_out, int out_size, void* d_ws, size_t ws_size,
                              hipStream_t stream) {
  const int*   seq   = (const int*)d_in[0];
  const float* emb   = (const float*)d_in[3];
  const float* e0f_Wih = (const float*)d_in[4];
  const float* e0f_Whh = (const float*)d_in[5];
  const float* e0f_bih = (const float*)d_in[6];
  const float* e0f_bhh = (const float*)d_in[7];
  const float* e0b_Wih = (const float*)d_in[8];
  const float* e0b_Whh = (const float*)d_in[9];
  const float* e0b_bih = (const float*)d_in[10];
  const float* e0b_bhh = (const float*)d_in[11];
  const float* e1f_Wih = (const float*)d_in[12];
  const float* e1f_Whh = (const float*)d_in[13];
  const float* e1f_bih = (const float*)d_in[14];
  const float* e1f_bhh = (const float*)d_in[15];
  const float* e1b_Wih = (const float*)d_in[16];
  const float* e1b_Whh = (const float*)d_in[17];
  const float* e1b_bih = (const float*)d_in[18];
  const float* e1b_bhh = (const float*)d_in[19];
  const float* dWih = (const float*)d_in[20];
  const float* dWhh = (const float*)d_in[21];
  const float* dbih = (const float*)d_in[22];
  const float* dbhh = (const float*)d_in[23];
  const float* cW   = (const float*)d_in[24];
  const float* cb   = (const float*)d_in[25];
  const float* outW = (const float*)d_in[26];
  const float* outb = (const float*)d_in[27];

  float* w = (float*)d_ws;
  float* ex      = w;                      // 128000
  float* x1      = ex + 128000;            // 256000
  float* gxf     = x1 + 256000;            // 384000
  float* gxb     = gxf + 384000;           // 384000
  float* y1f     = gxb + 384000;           // 128000
  float* y1b     = y1f + 128000;           // 128000
  float* enc_out = y1b + 128000;           // 128000
  float* hb      = enc_out + 128000;       // 8 x 512 (decoder h storage)
  float* hL0FA = hb;          float* hL0BA = hb + 512;
  float* dsc0   = hb + 1024;               // 512
  float* dsc1   = dsc0 + 512;              // 512
  float* scores = dsc1 + 512;              // 512
  float* ctx    = scores + 512;            // 512
  float* cvec   = ctx + 512;               // 512
  float* logits = cvec + 512;              // 50432
  float* pm     = logits + 50432;          // 256
  float* ps     = pm + 256;                // 256
  float* stats  = ps + 256;                // 192 (2 per step)
  int*   pix    = (int*)(stats + 192);     // 256 ints
  int*   tokp   = pix + 256;               // 64 ints
  int*   bar    = tokp + 64;               // 128 ints: dflags(64) + dcnt(64)
  int*   dflags = bar;
  int*   dcnt   = bar + 64;
  ull*   htag   = (ull*)(bar + 128);       // 8 regions x 512 ull = 32 KB
  ull* tL0F_A = htag;        ull* tL0F_B = htag + 512;
  ull* tL0B_A = htag + 1024; ull* tL0B_B = htag + 1536;
  ull* tL1F_A = htag + 2048; ull* tL1F_B = htag + 2560;
  ull* tL1B_A = htag + 3072; ull* tL1B_B = htag + 3584;

  float* outf = (float*)d_out;

  // zero sync flags + tag buffers (d_ws is re-poisoned before every call)
  hipMemsetAsync(bar, 0, 128 * sizeof(int) + 4096 * sizeof(ull), stream);

  init_k<<<1, 64, 0, stream>>>(tokp);
  embed_k<<<SEQ, 128, 0, stream>>>(seq, emb, ex);

  // encoder layer 0
  gemm_nt<<<dim3(24, 4), 256, 0, stream>>>(ex, e0f_Wih, e0f_bih, gxf, SEQ, H3, H);
  gemm_nt<<<dim3(24, 4), 256, 0, stream>>>(ex, e0b_Wih, e0b_bih, gxb, SEQ, H3, H);
  gru_scan_tag<<<2 * SB, 512, 0, stream>>>(gxf, gxb, e0f_Whh, e0b_Whh,
      e0f_bhh, e0b_bhh, tL0F_A, tL0F_B, tL0B_A, tL0B_B, x1, x1 + 500, 1000);
  // final layer-0 hidden states (in the A tag buffers: last write is t=255, odd)
  unpack_k<<<1, 512, 0, stream>>>(tL0F_A, tL0B_A, hL0FA, hL0BA);

  // encoder layer 1
  gemm_nt<<<dim3(24, 4), 256, 0, stream>>>(x1, e1f_Wih, e1f_bih, gxf, SEQ, H3, 2 * H);
  gemm_nt<<<dim3(24, 4), 256, 0, stream>>>(x1, e1b_Wih, e1b_bih, gxb, SEQ, H3, 2 * H);
  gru_scan_tag<<<2 * SB, 512, 0, stream>>>(gxf, gxb, e1f_Whh, e1b_Whh,
      e1f_bhh, e1b_bhh, tL1F_A, tL1F_B, tL1B_A, tL1B_B, y1f, y1b, 500);
  add_k<<<(SEQ * H + 255) / 256, 256, 0, stream>>>(y1f, y1b, enc_out, SEQ * H);

  // decoder: one launch per step; probs of step st written during step st+1
  float* h0c = hL0FA; float* h0a = dsc0;
  float* h1c = hL0BA; float* h1a = dsc1;
  for (int st = 0; st < TDEC; ++st) {
    dec_step_v4<<<NDB, 512, 0, stream>>>(tokp, emb, h0c, h0a, h1c, h1a,
        dWih, dWhh, dbih, dbhh, enc_out, cW, cb, outW, outb,
        scores, ctx, cvec, logits, pm, ps, pix, stats,
        outf, outf + TDEC, dflags, dcnt, st);
    float* t0 = h0c; h0c = h0a; h0a = t0;
    float* t1 = h1c; h1c = h1a; h1a = t1;
  }
  probs_k<<<NLT, 256, 0, stream>>>(logits, stats + 2 * (TDEC - 1),
      outf + TDEC + (size_t)(TDEC - 1) * V);
}

// Round 5
// 6294.265 us; speedup vs baseline: 1.3051x; 1.0913x over previous
//
#include <hip/hip_runtime.h>
#include <math.h>

typedef unsigned long long ull;

constexpr int H    = 500;
constexpr int H3   = 1500;
constexpr int SEQ  = 256;
constexpr int V    = 50257;
constexpr int TDEC = 64;
constexpr int NLT  = (V + 255) / 256;  // probs_k blocks (197)
constexpr int SB   = 50;               // scan blocks per direction
constexpr int UPB  = 10;               // hidden units per scan block
constexpr int NDB  = 256;              // decoder blocks
constexpr int VPB  = (V + NDB - 1) / NDB;  // 197 vocab rows per decoder block

__device__ __forceinline__ float sigmoidf_(float x) { return 1.f / (1.f + expf(-x)); }

__device__ __forceinline__ float wred(float v) {
  #pragma unroll
  for (int off = 32; off > 0; off >>= 1) v += __shfl_down(v, off, 64);
  return v;
}

// LLC-routed (sc1) scalar accesses for cross-block data WITHIN a launch.
__device__ __forceinline__ float gload(const float* p) {
  return __hip_atomic_load((float*)p, __ATOMIC_RELAXED, __HIP_MEMORY_SCOPE_AGENT);
}
__device__ __forceinline__ void gstore(float* p, float v) {
  __hip_atomic_store(p, v, __ATOMIC_RELAXED, __HIP_MEMORY_SCOPE_AGENT);
}
__device__ __forceinline__ int gload_i(const int* p) {
  return __hip_atomic_load((int*)p, __ATOMIC_RELAXED, __HIP_MEMORY_SCOPE_AGENT);
}
__device__ __forceinline__ ull gload64(const ull* p) {
  return __hip_atomic_load((ull*)p, __ATOMIC_RELAXED, __HIP_MEMORY_SCOPE_AGENT);
}
__device__ __forceinline__ void gstore64(ull* p, ull v) {
  __hip_atomic_store(p, v, __ATOMIC_RELAXED, __HIP_MEMORY_SCOPE_AGENT);
}

// ---------------- tagged-word polls: data arrival IS the sync ----------------
// wave0 polls N tagged words (tag in hi32) until all == want, then unpacks the
// float payloads into LDS. All other waves wait at the trailing barrier.
template<int N>
__device__ __forceinline__ void poll_tags(const ull* tags, unsigned want,
                                          float* dst, int tid) {
  constexpr int NW = (N + 63) / 64;
  if (tid < 64) {
    ull v[NW];
    bool ok;
    do {
      ok = true;
      #pragma unroll
      for (int j = 0; j < NW; ++j) {
        int k = tid + (j << 6);
        if (k < N) {
          v[j] = gload64(&tags[k]);
          if ((unsigned)(v[j] >> 32) != want) ok = false;
        }
      }
      if (!ok) __builtin_amdgcn_s_sleep(1);
    } while (!ok);
    #pragma unroll
    for (int j = 0; j < NW; ++j) {
      int k = tid + (j << 6);
      if (k < N) dst[k] = __uint_as_float((unsigned)v[j]);
    }
  }
  __syncthreads();
}

// poll two tag arrays (500 + 256) in one combined retry loop
__device__ __forceinline__ void poll2_tags(const ull* tA, float* dA,
                                           const ull* tB, float* dB,
                                           unsigned want, int tid) {
  if (tid < 64) {
    ull va[8], vb[4];
    bool ok;
    do {
      ok = true;
      #pragma unroll
      for (int j = 0; j < 8; ++j) {
        int k = tid + (j << 6);
        if (k < 500) {
          va[j] = gload64(&tA[k]);
          if ((unsigned)(va[j] >> 32) != want) ok = false;
        }
      }
      #pragma unroll
      for (int j = 0; j < 4; ++j) {
        int k = tid + (j << 6);
        vb[j] = gload64(&tB[k]);
        if ((unsigned)(vb[j] >> 32) != want) ok = false;
      }
      if (!ok) __builtin_amdgcn_s_sleep(1);
    } while (!ok);
    #pragma unroll
    for (int j = 0; j < 8; ++j) {
      int k = tid + (j << 6);
      if (k < 500) dA[k] = __uint_as_float((unsigned)va[j]);
    }
    #pragma unroll
    for (int j = 0; j < 4; ++j) {
      int k = tid + (j << 6);
      dB[k] = __uint_as_float((unsigned)vb[j]);
    }
  }
  __syncthreads();
}

// ---------------- init: tok = SOS ----------------
__global__ void init_k(int* tok) {
  if (threadIdx.x == 0) tok[0] = 1;  // SOS
}

// ---------------- embedding lookup: ex[t] = emb[seq[t]] ----------------
__global__ void embed_k(const int* __restrict__ seq, const float* __restrict__ emb,
                        float* __restrict__ ex) {
  int t = blockIdx.x;
  int tok = seq[t];
  for (int i = threadIdx.x; i < H; i += blockDim.x)
    ex[(size_t)t * H + i] = emb[(size_t)tok * H + i];
}

// ---------------- C[m][n] = bias[n] + sum_k X[m*K+k] * W[n*K+k] ----------------
__global__ __launch_bounds__(256) void gemm_nt(const float* __restrict__ X,
                                               const float* __restrict__ W,
                                               const float* __restrict__ bias,
                                               float* __restrict__ C,
                                               int M, int N, int K) {
  __shared__ float Xs[64][17];
  __shared__ float Ws[64][17];
  int bm = blockIdx.y * 64, bn = blockIdx.x * 64;
  int tid = threadIdx.x;
  int tx = tid % 16, ty = tid / 16;
  float acc[4][4] = {};
  for (int k0 = 0; k0 < K; k0 += 16) {
    for (int i = tid; i < 64 * 16; i += 256) {
      int m = i / 16, k = i % 16;
      int gm = bm + m, gk = k0 + k, gn = bn + m;
      Xs[m][k] = (gm < M && gk < K) ? X[(size_t)gm * K + gk] : 0.f;
      Ws[m][k] = (gn < N && gk < K) ? W[(size_t)gn * K + gk] : 0.f;
    }
    __syncthreads();
    #pragma unroll
    for (int k = 0; k < 16; ++k) {
      float xv[4], wv[4];
      #pragma unroll
      for (int i = 0; i < 4; ++i) xv[i] = Xs[ty * 4 + i][k];
      #pragma unroll
      for (int j = 0; j < 4; ++j) wv[j] = Ws[tx * 4 + j][k];
      #pragma unroll
      for (int i = 0; i < 4; ++i)
        #pragma unroll
        for (int j = 0; j < 4; ++j) acc[i][j] += xv[i] * wv[j];
    }
    __syncthreads();
  }
  for (int i = 0; i < 4; ++i) {
    int gm = bm + ty * 4 + i;
    if (gm >= M) continue;
    for (int j = 0; j < 4; ++j) {
      int gn = bn + tx * 4 + j;
      if (gn >= N) continue;
      C[(size_t)gm * N + gn] = acc[i][j] + bias[gn];
    }
  }
}

// ---------------- persistent GRU scan with TAGGED-H sync (verified R4) ----------------
__global__ __launch_bounds__(512, 1) void gru_scan_tag(
    const float* __restrict__ gxF, const float* __restrict__ gxB,
    const float* __restrict__ WhhF, const float* __restrict__ WhhB,
    const float* __restrict__ bhhF, const float* __restrict__ bhhB,
    ull* __restrict__ tAF, ull* __restrict__ tBF,
    ull* __restrict__ tAB, ull* __restrict__ tBB,
    float* __restrict__ yF, float* __restrict__ yB, int ystride) {
  __shared__ float w_lds[30 * 500];   // 60 KB
  __shared__ float gates[32];
  __shared__ float h_lds[512];
  int dir = blockIdx.x / SB;
  int bu  = blockIdx.x % SB;
  int u0  = bu * UPB;
  const float* gx  = dir ? gxB : gxF;
  const float* Whh = dir ? WhhB : WhhF;
  const float* bhh = dir ? bhhB : bhhF;
  ull* tagA = dir ? tAB : tAF;
  ull* tagB = dir ? tBB : tBF;
  float* y  = dir ? yB : yF;
  int tid = threadIdx.x, lane = tid & 63, wid = tid >> 6;

  for (int idx = tid; idx < 30 * 500; idx += 512) {
    int r = idx / 500, k = idx - r * 500;
    int g = r / UPB, lu = r - g * UPB;
    w_lds[idx] = Whh[(size_t)(g * 500 + u0 + lu) * 500 + k];
  }
  int u = u0 + tid;
  float br = 0.f, bz = 0.f, bn = 0.f;
  if (tid < UPB) { br = bhh[u]; bz = bhh[500 + u]; bn = bhh[1000 + u]; }
  h_lds[tid] = 0.f;
  __syncthreads();

  for (int t = 0; t < SEQ; ++t) {
    ull* wout = (t & 1) ? tagA : tagB;
    ull* win  = (t & 1) ? tagB : tagA;
    int teff = dir ? (SEQ - 1 - t) : t;

    float gxr = 0.f, gxz = 0.f, gxn = 0.f;
    if (tid < UPB) {
      const float* g = gx + (size_t)teff * H3;
      gxr = g[u]; gxz = g[500 + u]; gxn = g[1000 + u];
    }

    if (t > 0 && wid == 0) {
      ull v[8];
      for (;;) {
        bool ok = true;
        #pragma unroll
        for (int j = 0; j < 8; ++j) {
          int k = lane + 64 * j;
          if (k < 500) {
            v[j] = gload64(&win[k]);
            if ((unsigned)(v[j] >> 32) != (unsigned)t) ok = false;
          }
        }
        if (ok) break;
        __builtin_amdgcn_s_sleep(1);
      }
      #pragma unroll
      for (int j = 0; j < 8; ++j) {
        int k = lane + 64 * j;
        if (k < 500) h_lds[k] = __uint_as_float((unsigned)v[j]);
      }
    }
    __syncthreads();

    float hreg[8];
    #pragma unroll
    for (int j = 0; j < 8; ++j) {
      int k = lane + 64 * j;
      hreg[j] = (k < 500) ? h_lds[k] : 0.f;
    }
    for (int r = wid; r < 30; r += 8) {
      const float* wr = &w_lds[r * 500];
      float acc = 0.f;
      #pragma unroll
      for (int j = 0; j < 8; ++j) {
        int k = lane + 64 * j;
        if (k < 500) acc += wr[k] * hreg[j];
      }
      acc = wred(acc);
      if (lane == 0) gates[r] = acc;
    }
    __syncthreads();
    if (tid < UPB) {
      float hold = h_lds[u];
      float rr = sigmoidf_(gxr + gates[tid]           + br);
      float zz = sigmoidf_(gxz + gates[UPB + tid]     + bz);
      float nn = tanhf(    gxn + rr * (gates[2 * UPB + tid] + bn));
      float hp = (1.f - zz) * nn + zz * hold;
      ull pv = ((ull)(unsigned)(t + 1) << 32) | (ull)__float_as_uint(hp);
      gstore64(&wout[u], pv);
      y[(size_t)teff * ystride + u] = hp;
    }
  }
}

// ---------------- unpack final layer-0 hidden states for the decoder ----------------
__global__ void unpack_k(const ull* __restrict__ ta, const ull* __restrict__ tb,
                         float* __restrict__ ha, float* __restrict__ hb_) {
  int i = threadIdx.x;
  if (i < 500) {
    ha[i]  = __uint_as_float((unsigned)ta[i]);
    hb_[i] = __uint_as_float((unsigned)tb[i]);
  }
}

// ---------------- enc_out = y1f + y1b ----------------
__global__ void add_k(const float* __restrict__ a, const float* __restrict__ b,
                      float* __restrict__ c, int n) {
  int i = blockIdx.x * blockDim.x + threadIdx.x;
  if (i < n) c[i] = a[i] + b[i];
}

// ---------------- per-unit GRU cell; publishes tagged + plain ----------------
__device__ __forceinline__ void cell_unit_pub(int u, int lane,
    const float* xf, const float* hf,
    const float* __restrict__ Wih, const float* __restrict__ Whh,
    const float* __restrict__ bih, const float* __restrict__ bhh,
    float* hplain, ull* htag, unsigned want) {
  float g[6];
  #pragma unroll
  for (int kind = 0; kind < 6; ++kind) {
    const float* row = (kind < 3) ? (Wih + (size_t)(kind * 500 + u) * 500)
                                  : (Whh + (size_t)((kind - 3) * 500 + u) * 500);
    const float* vec = (kind < 3) ? xf : hf;
    float acc = 0.f;
    #pragma unroll
    for (int j = 0; j < 8; ++j) {
      int k = lane + 64 * j;
      if (k < 500) acc += row[k] * vec[k];
    }
    g[kind] = wred(acc);
  }
  if (lane == 0) {
    float r = sigmoidf_(g[0] + bih[u]        + g[3] + bhh[u]);
    float z = sigmoidf_(g[1] + bih[500 + u]  + g[4] + bhh[500 + u]);
    float n = tanhf(    g[2] + bih[1000 + u] + r * (g[5] + bhh[1000 + u]));
    float hv = (1.f - z) * n + z * hf[u];
    hplain[u] = hv;                      // next launch reads plain
    gstore64(&htag[u], ((ull)want << 32) | (ull)__float_as_uint(hv));
  }
}

// ---------------- decoder step: pure dataflow, zero barriers ----------------
// workers = blocks 0..62 (unit-per-wave). tag chain per step (tag = st+1):
//   A: th0   B: th1   C(blk<32): tsc   D: tctx   E: tcvec   F: all 256 blocks.
// prev-step probs: idlers at entry, workers at exit (logits ping-pong).
__global__ __launch_bounds__(512, 1) void dec_step_v5(
    int* __restrict__ tokp, const float* __restrict__ emb,
    const float* __restrict__ h0in, float* __restrict__ h0out,
    const float* __restrict__ h1in, float* __restrict__ h1out,
    const float* __restrict__ dWih, const float* __restrict__ dWhh,
    const float* __restrict__ dbih, const float* __restrict__ dbhh,
    const float* __restrict__ enc_out, const float* __restrict__ cW,
    const float* __restrict__ cb,
    const float* __restrict__ outW, const float* __restrict__ outb,
    ull* __restrict__ th0, ull* __restrict__ th1, ull* __restrict__ tsc,
    ull* __restrict__ tctx, ull* __restrict__ tcvec,
    float* __restrict__ lg_w, const float* __restrict__ lg_r,
    float* __restrict__ pm, float* __restrict__ ps, int* __restrict__ pix,
    float* __restrict__ stats, float* __restrict__ out_tokens,
    float* __restrict__ out_probs, int* __restrict__ dcnt, int st) {
  __shared__ float4 v4[250];           // xf[0..500) + hf[500..1000) contiguous
  __shared__ float hfull[512];         // rnn = h1 (kept for E)
  __shared__ float red[256], sc[256];
  __shared__ float wm[8], wsum[8]; __shared__ int wix[8];
  __shared__ float mm[256], ms[256]; __shared__ int mi[256];
  __shared__ int lastf;
  float* xf = (float*)v4;
  float* hf = xf + 500;
  int tid = threadIdx.x, lane = tid & 63, wid = tid >> 6, blk = blockIdx.x;
  unsigned want = (unsigned)(st + 1);
  bool worker = blk < 63;
  int u = blk * 8 + wid;

  // ---- idle blocks: prev-step probs now (block-private rows, logits ping-pong) ----
  if (!worker && st > 0) {
    float mM = stats[2 * (st - 1)], iS = stats[2 * (st - 1) + 1];
    int base = blk * VPB;
    for (int r = tid; r < VPB; r += 512) {
      int v = base + r;
      if (v < V) out_probs[(size_t)(st - 1) * V + v] = expf(lg_r[v] - mM) * iS;
    }
  }

  if (worker) {
    // ---- A: layer-0 cell ----
    int tk = tokp[0];                       // plain: prev launch merge
    for (int i = tid; i < 500; i += 512) {
      xf[i] = emb[(size_t)tk * 500 + i];
      hf[i] = h0in[i];
    }
    __syncthreads();
    if (u < 500) cell_unit_pub(u, lane, xf, hf, dWih, dWhh, dbih, dbhh,
                               h0out, th0, want);
    __syncthreads();                        // A reads of xf/hf done

    // ---- B: layer-1 cell ----
    if (tid >= 64) for (int i = tid - 64; i < 500; i += 448) hf[i] = h1in[i];
    poll_tags<500>(th0, want, xf, tid);     // xf = h0 (tagged arrivals)
    if (u < 500) cell_unit_pub(u, lane, xf, hf,
        dWih + 750000, dWhh + 750000, dbih + 1500, dbhh + 1500,
        h1out, th1, want);
    __syncthreads();                        // B reads done

    // ---- C: attention scores (blocks 0..31; 1 wave per score) ----
    if (blk < 32) {
      poll_tags<500>(th1, want, hfull, tid);
      int s = blk * 8 + wid;
      const float* row = enc_out + (size_t)s * 500;
      float acc = 0.f;
      #pragma unroll
      for (int j = 0; j < 8; ++j) {
        int k = lane + 64 * j;
        if (k < 500) acc += row[k] * hfull[k];
      }
      acc = wred(acc);
      if (lane == 0)
        gstore64(&tsc[s], ((ull)want << 32) | (ull)__float_as_uint(acc));
      // ---- D-poll: scores only (h1 already in hfull) ----
      poll_tags<256>(tsc, want, sc, tid);
    } else {
      // ---- D-poll: h1 + scores combined ----
      poll2_tags(th1, hfull, tsc, sc, want, tid);
    }

    // ---- D: softmax (local, identical in all workers) + ctx (8 cols/block) ----
    {
      float myv = (tid < 256) ? sc[tid] : 0.f;
      if (tid < 256) red[tid] = myv;
      __syncthreads();
      for (int s = 128; s > 0; s >>= 1) {
        if (tid < s) red[tid] = fmaxf(red[tid], red[tid + s]);
        __syncthreads();
      }
      float m = red[0]; __syncthreads();
      float e = 0.f;
      if (tid < 256) { e = expf(myv - m); red[tid] = e; }
      __syncthreads();
      for (int s = 128; s > 0; s >>= 1) {
        if (tid < s) red[tid] += red[tid + s];
        __syncthreads();
      }
      float inv = 1.f / red[0]; __syncthreads();
      if (tid < 256) sc[tid] = e * inv;
      __syncthreads();
      int j = blk * 8 + wid;
      if (j < 500) {
        float acc = 0.f;
        #pragma unroll
        for (int q = 0; q < 4; ++q) {
          int s = lane + 64 * q;
          acc += sc[s] * enc_out[(size_t)s * 500 + j];
        }
        acc = wred(acc);
        if (lane == 0)
          gstore64(&tctx[j], ((ull)want << 32) | (ull)__float_as_uint(acc));
      }
    }

    // ---- E: cvec (8 rows/block); xf = rnn, hf = ctx (contiguous 1000) ----
    if (tid >= 64) for (int i = tid - 64; i < 500; i += 448) xf[i] = hfull[i];
    poll_tags<500>(tctx, want, hf, tid);
    {
      int i = blk * 8 + wid;
      if (i < 500) {
        const float* row = cW + (size_t)i * 1000;
        float acc = 0.f;
        #pragma unroll
        for (int j = 0; j < 16; ++j) {
          int k = lane + 64 * j;
          if (k < 1000) acc += row[k] * xf[k];
        }
        acc = wred(acc);
        if (lane == 0) {
          float cv = tanhf(acc + cb[i]);
          gstore64(&tcvec[i], ((ull)want << 32) | (ull)__float_as_uint(cv));
        }
      }
    }
    __syncthreads();                        // E reads of xf/hf done
  }

  // ---- F: all 256 blocks — logits rows + online-softmax partials ----
  poll_tags<500>(tcvec, want, xf, tid);
  const float4* c4 = v4;
  {
    int lstart = wid * 25, lend = (wid + 1) * 25; if (lend > VPB) lend = VPB;
    int r0 = blk * VPB + lstart, r1 = blk * VPB + lend; if (r1 > V) r1 = V;
    float m = -1e30f, ssum = 0.f; int ix = V;
    for (int rb = r0; rb < r1; rb += 4) {
      int nr = r1 - rb; if (nr > 4) nr = 4;
      float a[4] = {0.f, 0.f, 0.f, 0.f};
      #pragma unroll
      for (int q = 0; q < 2; ++q) {
        int k4 = lane + 64 * q;
        if (k4 < 125) {
          float4 cc = c4[k4];
          #pragma unroll
          for (int rr = 0; rr < 4; ++rr) {
            if (rr < nr) {
              float4 w4 = ((const float4*)(outW + (size_t)(rb + rr) * 500))[k4];
              a[rr] += w4.x * cc.x + w4.y * cc.y + w4.z * cc.z + w4.w * cc.w;
            }
          }
        }
      }
      #pragma unroll
      for (int rr = 0; rr < 4; ++rr) {
        if (rr < nr) {
          float l = wred(a[rr]);
          if (lane == 0) {
            l += outb[rb + rr];
            lg_w[rb + rr] = l;     // plain: next launch phase-P reads
            if (l > m) { ssum = ssum * expf(m - l) + 1.f; m = l; ix = rb + rr; }
            else       { ssum += expf(l - m); }
          }
        }
      }
    }
    if (lane == 0) { wm[wid] = m; wsum[wid] = ssum; wix[wid] = ix; }
  }
  __syncthreads();
  if (tid == 0) {
    float M = wm[0], S = wsum[0]; int I = wix[0];
    for (int w = 1; w < 8; ++w) {
      if (wm[w] > M) { S = S * expf(M - wm[w]) + wsum[w]; M = wm[w]; I = wix[w]; }
      else           { S += wsum[w] * expf(wm[w] - M); }
    }
    gstore(&pm[blk], M); gstore(&ps[blk], S);
    __hip_atomic_store(&pix[blk], I, __ATOMIC_RELAXED, __HIP_MEMORY_SCOPE_AGENT);
    __builtin_amdgcn_s_waitcnt(0);          // partials at LLC before the count
    int prev = __hip_atomic_fetch_add(&dcnt[st], 1, __ATOMIC_RELAXED,
                                      __HIP_MEMORY_SCOPE_AGENT);
    lastf = (prev == NDB - 1) ? 1 : 0;
  }
  __syncthreads();

  // ---- last-done block merges partials -> token, stats ----
  if (lastf) {
    if (tid < 256) { mm[tid] = gload(&pm[tid]); ms[tid] = gload(&ps[tid]); mi[tid] = gload_i(&pix[tid]); }
    __syncthreads();
    for (int s = 128; s > 0; s >>= 1) {
      if (tid < s) {
        float ma = mm[tid], mb = mm[tid + s];
        float sa = ms[tid], sb = ms[tid + s];
        int ia = mi[tid], ib = mi[tid + s];
        if (mb > ma || (mb == ma && ib < ia)) {
          ms[tid] = sa * expf(ma - mb) + sb; mm[tid] = mb; mi[tid] = ib;
        } else {
          ms[tid] = sa + sb * expf(mb - ma);
        }
      }
      __syncthreads();
    }
    if (tid == 0) {
      tokp[0] = mi[0];
      out_tokens[st] = (float)mi[0];
      stats[2 * st] = mm[0];
      stats[2 * st + 1] = 1.f / ms[0];
    }
  }

  // ---- workers: prev-step probs at exit (off the critical path) ----
  if (worker && st > 0) {
    float mM = stats[2 * (st - 1)], iS = stats[2 * (st - 1) + 1];
    int base = blk * VPB;
    for (int r = tid; r < VPB; r += 512) {
      int v = base + r;
      if (v < V) out_probs[(size_t)(st - 1) * V + v] = expf(lg_r[v] - mM) * iS;
    }
  }
}

// ---------------- wide probs write for the final step ----------------
__global__ __launch_bounds__(256) void probs_k(const float* __restrict__ logits,
    const float* __restrict__ stats, float* __restrict__ out_probs) {
  int v = blockIdx.x * 256 + threadIdx.x;
  if (v < V) out_probs[v] = expf(logits[v] - stats[0]) * stats[1];
}

extern "C" void kernel_launch(void* const* d_in, const int* in_sizes, int n_in,
                              void* d_out, int out_size, void* d_ws, size_t ws_size,
                              hipStream_t stream) {
  const int*   seq   = (const int*)d_in[0];
  const float* emb   = (const float*)d_in[3];
  const float* e0f_Wih = (const float*)d_in[4];
  const float* e0f_Whh = (const float*)d_in[5];
  const float* e0f_bih = (const float*)d_in[6];
  const float* e0f_bhh = (const float*)d_in[7];
  const float* e0b_Wih = (const float*)d_in[8];
  const float* e0b_Whh = (const float*)d_in[9];
  const float* e0b_bih = (const float*)d_in[10];
  const float* e0b_bhh = (const float*)d_in[11];
  const float* e1f_Wih = (const float*)d_in[12];
  const float* e1f_Whh = (const float*)d_in[13];
  const float* e1f_bih = (const float*)d_in[14];
  const float* e1f_bhh = (const float*)d_in[15];
  const float* e1b_Wih = (const float*)d_in[16];
  const float* e1b_Whh = (const float*)d_in[17];
  const float* e1b_bih = (const float*)d_in[18];
  const float* e1b_bhh = (const float*)d_in[19];
  const float* dWih = (const float*)d_in[20];
  const float* dWhh = (const float*)d_in[21];
  const float* dbih = (const float*)d_in[22];
  const float* dbhh = (const float*)d_in[23];
  const float* cW   = (const float*)d_in[24];
  const float* cb   = (const float*)d_in[25];
  const float* outW = (const float*)d_in[26];
  const float* outb = (const float*)d_in[27];

  float* w = (float*)d_ws;
  float* ex      = w;                      // 128000
  float* x1      = ex + 128000;            // 256000
  float* gxf     = x1 + 256000;            // 384000
  float* gxb     = gxf + 384000;           // 384000
  float* y1f     = gxb + 384000;           // 128000
  float* y1b     = y1f + 128000;           // 128000
  float* enc_out = y1b + 128000;           // 128000
  float* hL0FA   = enc_out + 128000;       // 512
  float* hL0BA   = hL0FA + 512;            // 512
  float* dsc0    = hL0BA + 512;            // 512
  float* dsc1    = dsc0 + 512;             // 512
  float* lg0     = dsc1 + 512;             // 50432
  float* lg1     = lg0 + 50432;            // 50432
  float* pm      = lg1 + 50432;            // 256
  float* ps      = pm + 256;               // 256
  float* stats   = ps + 256;               // 192 (2 per step)
  int*   pix     = (int*)(stats + 192);    // 256 ints
  int*   tokp    = pix + 256;              // 64 ints
  int*   dcnt    = tokp + 64;              // 64 ints
  ull*   htag    = (ull*)(dcnt + 64);      // scan tags: 4096 ull (8B-aligned)
  ull* tL0F_A = htag;        ull* tL0F_B = htag + 512;
  ull* tL0B_A = htag + 1024; ull* tL0B_B = htag + 1536;
  ull* tL1F_A = htag + 2048; ull* tL1F_B = htag + 2560;
  ull* tL1B_A = htag + 3072; ull* tL1B_B = htag + 3584;
  ull*   dtag    = htag + 4096;            // decoder tags: 2304 ull
  ull* th0   = dtag;        ull* th1  = dtag + 512;
  ull* tsc   = dtag + 1024; ull* tctx = dtag + 1280;
  ull* tcvec = dtag + 1792;

  float* outf = (float*)d_out;

  // zero dcnt + all tag buffers (d_ws is re-poisoned before every call)
  hipMemsetAsync(dcnt, 0, 64 * sizeof(int) + 6400 * sizeof(ull), stream);

  init_k<<<1, 64, 0, stream>>>(tokp);
  embed_k<<<SEQ, 128, 0, stream>>>(seq, emb, ex);

  // encoder layer 0
  gemm_nt<<<dim3(24, 4), 256, 0, stream>>>(ex, e0f_Wih, e0f_bih, gxf, SEQ, H3, H);
  gemm_nt<<<dim3(24, 4), 256, 0, stream>>>(ex, e0b_Wih, e0b_bih, gxb, SEQ, H3, H);
  gru_scan_tag<<<2 * SB, 512, 0, stream>>>(gxf, gxb, e0f_Whh, e0b_Whh,
      e0f_bhh, e0b_bhh, tL0F_A, tL0F_B, tL0B_A, tL0B_B, x1, x1 + 500, 1000);
  unpack_k<<<1, 512, 0, stream>>>(tL0F_A, tL0B_A, hL0FA, hL0BA);

  // encoder layer 1
  gemm_nt<<<dim3(24, 4), 256, 0, stream>>>(x1, e1f_Wih, e1f_bih, gxf, SEQ, H3, 2 * H);
  gemm_nt<<<dim3(24, 4), 256, 0, stream>>>(x1, e1b_Wih, e1b_bih, gxb, SEQ, H3, 2 * H);
  gru_scan_tag<<<2 * SB, 512, 0, stream>>>(gxf, gxb, e1f_Whh, e1b_Whh,
      e1f_bhh, e1b_bhh, tL1F_A, tL1F_B, tL1B_A, tL1B_B, y1f, y1b, 500);
  add_k<<<(SEQ * H + 255) / 256, 256, 0, stream>>>(y1f, y1b, enc_out, SEQ * H);

  // decoder: one dataflow launch per step; probs(st) written during step st+1
  float* h0c = hL0FA; float* h0a = dsc0;
  float* h1c = hL0BA; float* h1a = dsc1;
  for (int st = 0; st < TDEC; ++st) {
    float* lg_w = (st & 1) ? lg1 : lg0;
    float* lg_r = (st & 1) ? lg0 : lg1;
    dec_step_v5<<<NDB, 512, 0, stream>>>(tokp, emb, h0c, h0a, h1c, h1a,
        dWih, dWhh, dbih, dbhh, enc_out, cW, cb, outW, outb,
        th0, th1, tsc, tctx, tcvec, lg_w, lg_r,
        pm, ps, pix, stats, outf, outf + TDEC, dcnt, st);
    float* t0 = h0c; h0c = h0a; h0a = t0;
    float* t1 = h1c; h1c = h1a; h1a = t1;
  }
  probs_k<<<NLT, 256, 0, stream>>>(((TDEC - 1) & 1) ? lg1 : lg0,
      stats + 2 * (TDEC - 1), outf + TDEC + (size_t)(TDEC - 1) * V);
}

// Round 6
// 6212.280 us; speedup vs baseline: 1.3224x; 1.0132x over previous
//
#include <hip/hip_runtime.h>
#include <math.h>

typedef unsigned long long ull;

constexpr int H    = 500;
constexpr int H3   = 1500;
constexpr int SEQ  = 256;
constexpr int V    = 50257;
constexpr int TDEC = 64;
constexpr int NLT  = (V + 255) / 256;  // probs_k blocks (197)
constexpr int SB   = 50;               // scan blocks per direction
constexpr int UPB  = 10;               // hidden units per scan block
constexpr int NDB  = 256;              // decoder blocks
constexpr int VPB  = (V + NDB - 1) / NDB;  // 197 vocab rows per decoder block

__device__ __forceinline__ float sigmoidf_(float x) { return 1.f / (1.f + expf(-x)); }

__device__ __forceinline__ float wred(float v) {
  #pragma unroll
  for (int off = 32; off > 0; off >>= 1) v += __shfl_down(v, off, 64);
  return v;
}

// LLC-routed (sc1) scalar accesses for cross-block data WITHIN a launch.
__device__ __forceinline__ float gload(const float* p) {
  return __hip_atomic_load((float*)p, __ATOMIC_RELAXED, __HIP_MEMORY_SCOPE_AGENT);
}
__device__ __forceinline__ void gstore(float* p, float v) {
  __hip_atomic_store(p, v, __ATOMIC_RELAXED, __HIP_MEMORY_SCOPE_AGENT);
}
__device__ __forceinline__ int gload_i(const int* p) {
  return __hip_atomic_load((int*)p, __ATOMIC_RELAXED, __HIP_MEMORY_SCOPE_AGENT);
}
__device__ __forceinline__ ull gload64(const ull* p) {
  return __hip_atomic_load((ull*)p, __ATOMIC_RELAXED, __HIP_MEMORY_SCOPE_AGENT);
}
__device__ __forceinline__ void gstore64(ull* p, ull v) {
  __hip_atomic_store(p, v, __ATOMIC_RELAXED, __HIP_MEMORY_SCOPE_AGENT);
}

// ---------------- tagged-word polls: data arrival IS the sync ----------------
template<int N>
__device__ __forceinline__ void poll_tags(const ull* tags, unsigned want,
                                          float* dst, int tid) {
  constexpr int NW = (N + 63) / 64;
  if (tid < 64) {
    ull v[NW];
    bool ok;
    do {
      ok = true;
      #pragma unroll
      for (int j = 0; j < NW; ++j) {
        int k = tid + (j << 6);
        if (k < N) {
          v[j] = gload64(&tags[k]);
          if ((unsigned)(v[j] >> 32) != want) ok = false;
        }
      }
      if (!ok) __builtin_amdgcn_s_sleep(1);
    } while (!ok);
    #pragma unroll
    for (int j = 0; j < NW; ++j) {
      int k = tid + (j << 6);
      if (k < N) dst[k] = __uint_as_float((unsigned)v[j]);
    }
  }
  __syncthreads();
}

// poll two tag arrays (500 + 256) in one combined retry loop
__device__ __forceinline__ void poll2_tags(const ull* tA, float* dA,
                                           const ull* tB, float* dB,
                                           unsigned want, int tid) {
  if (tid < 64) {
    ull va[8], vb[4];
    bool ok;
    do {
      ok = true;
      #pragma unroll
      for (int j = 0; j < 8; ++j) {
        int k = tid + (j << 6);
        if (k < 500) {
          va[j] = gload64(&tA[k]);
          if ((unsigned)(va[j] >> 32) != want) ok = false;
        }
      }
      #pragma unroll
      for (int j = 0; j < 4; ++j) {
        int k = tid + (j << 6);
        vb[j] = gload64(&tB[k]);
        if ((unsigned)(vb[j] >> 32) != want) ok = false;
      }
      if (!ok) __builtin_amdgcn_s_sleep(1);
    } while (!ok);
    #pragma unroll
    for (int j = 0; j < 8; ++j) {
      int k = tid + (j << 6);
      if (k < 500) dA[k] = __uint_as_float((unsigned)va[j]);
    }
    #pragma unroll
    for (int j = 0; j < 4; ++j) {
      int k = tid + (j << 6);
      dB[k] = __uint_as_float((unsigned)vb[j]);
    }
  }
  __syncthreads();
}

// ---------------- init: ttok = {tag 1, SOS} ----------------
__global__ void init_k(ull* ttok) {
  if (threadIdx.x == 0) ttok[0] = (1ull << 32) | 1ull;
}

// ---------------- embedding lookup: ex[t] = emb[seq[t]] ----------------
__global__ void embed_k(const int* __restrict__ seq, const float* __restrict__ emb,
                        float* __restrict__ ex) {
  int t = blockIdx.x;
  int tok = seq[t];
  for (int i = threadIdx.x; i < H; i += blockDim.x)
    ex[(size_t)t * H + i] = emb[(size_t)tok * H + i];
}

// ---------------- C[m][n] = bias[n] + sum_k X[m*K+k] * W[n*K+k] ----------------
__global__ __launch_bounds__(256) void gemm_nt(const float* __restrict__ X,
                                               const float* __restrict__ W,
                                               const float* __restrict__ bias,
                                               float* __restrict__ C,
                                               int M, int N, int K) {
  __shared__ float Xs[64][17];
  __shared__ float Ws[64][17];
  int bm = blockIdx.y * 64, bn = blockIdx.x * 64;
  int tid = threadIdx.x;
  int tx = tid % 16, ty = tid / 16;
  float acc[4][4] = {};
  for (int k0 = 0; k0 < K; k0 += 16) {
    for (int i = tid; i < 64 * 16; i += 256) {
      int m = i / 16, k = i % 16;
      int gm = bm + m, gk = k0 + k, gn = bn + m;
      Xs[m][k] = (gm < M && gk < K) ? X[(size_t)gm * K + gk] : 0.f;
      Ws[m][k] = (gn < N && gk < K) ? W[(size_t)gn * K + gk] : 0.f;
    }
    __syncthreads();
    #pragma unroll
    for (int k = 0; k < 16; ++k) {
      float xv[4], wv[4];
      #pragma unroll
      for (int i = 0; i < 4; ++i) xv[i] = Xs[ty * 4 + i][k];
      #pragma unroll
      for (int j = 0; j < 4; ++j) wv[j] = Ws[tx * 4 + j][k];
      #pragma unroll
      for (int i = 0; i < 4; ++i)
        #pragma unroll
        for (int j = 0; j < 4; ++j) acc[i][j] += xv[i] * wv[j];
    }
    __syncthreads();
  }
  for (int i = 0; i < 4; ++i) {
    int gm = bm + ty * 4 + i;
    if (gm >= M) continue;
    for (int j = 0; j < 4; ++j) {
      int gn = bn + tx * 4 + j;
      if (gn >= N) continue;
      C[(size_t)gm * N + gn] = acc[i][j] + bias[gn];
    }
  }
}

// ---------------- persistent GRU scan, tagged-h sync, Whh in REGISTERS ----------------
// Rows r = wid + 8*rr (rr<4), k-slices k = lane + 64*j -> 32 VGPR weights/thread.
// Summation order identical to the R4-verified LDS version (bit-exact).
__global__ __launch_bounds__(512, 1) void gru_scan_tag(
    const float* __restrict__ gxF, const float* __restrict__ gxB,
    const float* __restrict__ WhhF, const float* __restrict__ WhhB,
    const float* __restrict__ bhhF, const float* __restrict__ bhhB,
    ull* __restrict__ tAF, ull* __restrict__ tBF,
    ull* __restrict__ tAB, ull* __restrict__ tBB,
    float* __restrict__ yF, float* __restrict__ yB, int ystride) {
  __shared__ float gates[32];
  __shared__ float h_lds[512];
  int dir = blockIdx.x / SB;
  int bu  = blockIdx.x % SB;
  int u0  = bu * UPB;
  const float* gx  = dir ? gxB : gxF;
  const float* Whh = dir ? WhhB : WhhF;
  const float* bhh = dir ? bhhB : bhhF;
  ull* tagA = dir ? tAB : tAF;
  ull* tagB = dir ? tBB : tBF;
  float* y  = dir ? yB : yF;
  int tid = threadIdx.x, lane = tid & 63, wid = tid >> 6;

  // register-resident Whh slice for this thread
  float wreg[4][8];
  #pragma unroll
  for (int rr = 0; rr < 4; ++rr) {
    int r = wid + 8 * rr;
    #pragma unroll
    for (int j = 0; j < 8; ++j) {
      int k = lane + 64 * j;
      wreg[rr][j] = (r < 30 && k < 500)
          ? Whh[(size_t)((r / UPB) * 500 + u0 + (r % UPB)) * 500 + k] : 0.f;
    }
  }
  int u = u0 + tid;
  float br = 0.f, bz = 0.f, bn = 0.f;
  if (tid < UPB) { br = bhh[u]; bz = bhh[500 + u]; bn = bhh[1000 + u]; }
  h_lds[tid] = 0.f;
  __syncthreads();

  for (int t = 0; t < SEQ; ++t) {
    ull* wout = (t & 1) ? tagA : tagB;
    ull* win  = (t & 1) ? tagB : tagA;
    int teff = dir ? (SEQ - 1 - t) : t;

    float gxr = 0.f, gxz = 0.f, gxn = 0.f;
    if (tid < UPB) {
      const float* g = gx + (size_t)teff * H3;
      gxr = g[u]; gxz = g[500 + u]; gxn = g[1000 + u];
    }

    if (t > 0 && wid == 0) {
      ull v[8];
      for (;;) {
        bool ok = true;
        #pragma unroll
        for (int j = 0; j < 8; ++j) {
          int k = lane + 64 * j;
          if (k < 500) {
            v[j] = gload64(&win[k]);
            if ((unsigned)(v[j] >> 32) != (unsigned)t) ok = false;
          }
        }
        if (ok) break;
        __builtin_amdgcn_s_sleep(1);
      }
      #pragma unroll
      for (int j = 0; j < 8; ++j) {
        int k = lane + 64 * j;
        if (k < 500) h_lds[k] = __uint_as_float((unsigned)v[j]);
      }
    }
    __syncthreads();

    float hreg[8];
    #pragma unroll
    for (int j = 0; j < 8; ++j) {
      int k = lane + 64 * j;
      hreg[j] = (k < 500) ? h_lds[k] : 0.f;
    }
    #pragma unroll
    for (int rr = 0; rr < 4; ++rr) {
      int r = wid + 8 * rr;
      if (r < 30) {
        float acc = 0.f;
        #pragma unroll
        for (int j = 0; j < 8; ++j) acc += wreg[rr][j] * hreg[j];
        acc = wred(acc);
        if (lane == 0) gates[r] = acc;
      }
    }
    __syncthreads();
    if (tid < UPB) {
      float hold = h_lds[u];
      float rr = sigmoidf_(gxr + gates[tid]           + br);
      float zz = sigmoidf_(gxz + gates[UPB + tid]     + bz);
      float nn = tanhf(    gxn + rr * (gates[2 * UPB + tid] + bn));
      float hp = (1.f - zz) * nn + zz * hold;
      ull pv = ((ull)(unsigned)(t + 1) << 32) | (ull)__float_as_uint(hp);
      gstore64(&wout[u], pv);
      y[(size_t)teff * ystride + u] = hp;
    }
    __syncthreads();
  }
}

// ---------------- seed decoder h tags from encoder layer-0 finals (tag 0) -------------
__global__ void seed_k(const ull* __restrict__ tf, const ull* __restrict__ tb,
                       ull* __restrict__ th0a, ull* __restrict__ th1a) {
  int i = threadIdx.x;
  if (i < 500) {
    th0a[i] = (ull)(unsigned)tf[i];   // payload, tag 0
    th1a[i] = (ull)(unsigned)tb[i];
  }
}

// ---------------- enc_out = y1f + y1b ----------------
__global__ void add_k(const float* __restrict__ a, const float* __restrict__ b,
                      float* __restrict__ c, int n) {
  int i = blockIdx.x * blockDim.x + threadIdx.x;
  if (i < n) c[i] = a[i] + b[i];
}

// ---------------- per-unit GRU cell; publishes tagged only ----------------
__device__ __forceinline__ void cell_unit_tag(int u, int lane,
    const float* xf, const float* hf,
    const float* __restrict__ Wih, const float* __restrict__ Whh,
    const float* __restrict__ bih, const float* __restrict__ bhh,
    ull* htag, unsigned want) {
  float g[6];
  #pragma unroll
  for (int kind = 0; kind < 6; ++kind) {
    const float* row = (kind < 3) ? (Wih + (size_t)(kind * 500 + u) * 500)
                                  : (Whh + (size_t)((kind - 3) * 500 + u) * 500);
    const float* vec = (kind < 3) ? xf : hf;
    float acc = 0.f;
    #pragma unroll
    for (int j = 0; j < 8; ++j) {
      int k = lane + 64 * j;
      if (k < 500) acc += row[k] * vec[k];
    }
    g[kind] = wred(acc);
  }
  if (lane == 0) {
    float r = sigmoidf_(g[0] + bih[u]        + g[3] + bhh[u]);
    float z = sigmoidf_(g[1] + bih[500 + u]  + g[4] + bhh[500 + u]);
    float n = tanhf(    g[2] + bih[1000 + u] + r * (g[5] + bhh[1000 + u]));
    float hv = (1.f - z) * n + z * hf[u];
    gstore64(&htag[u], ((ull)want << 32) | (ull)__float_as_uint(hv));
  }
}

// ---------------- PERSISTENT decoder: one launch, all 64 steps ----------------
// Gating invariant: any buffer overwrite at step st+1 is transitively gated
// through ttok(st+2 wait)->merge(st)->dcnt(st)=256->F(st) of all blocks, which
// in program order follows all reads of step-st data. Logits buffers are
// block-local (same rows written and read by the same block) -> plain accesses.
__global__ __launch_bounds__(512, 1) void dec_persist(
    const float* __restrict__ emb,
    const float* __restrict__ dWih, const float* __restrict__ dWhh,
    const float* __restrict__ dbih, const float* __restrict__ dbhh,
    const float* __restrict__ enc_out, const float* __restrict__ cW,
    const float* __restrict__ cb,
    const float* __restrict__ outW, const float* __restrict__ outb,
    ull* __restrict__ th0a, ull* __restrict__ th0b,
    ull* __restrict__ th1a, ull* __restrict__ th1b,
    ull* __restrict__ tsc, ull* __restrict__ tctx, ull* __restrict__ tcvec,
    ull* __restrict__ ttok,
    float* __restrict__ lg0, float* __restrict__ lg1,
    float* __restrict__ pm, float* __restrict__ ps, int* __restrict__ pix,
    float* __restrict__ stats, float* __restrict__ out_tokens,
    float* __restrict__ out_probs, int* __restrict__ dcnt) {
  __shared__ float4 v4[250];           // xf[0..500) + hf[500..1000)
  __shared__ float hfull[512];
  __shared__ float red[256], sc[256];
  __shared__ float wm[8], wsum[8]; __shared__ int wix[8];
  __shared__ float mm[256], ms[256]; __shared__ int mi[256];
  __shared__ int lastf, sh_tk;
  float* xf = (float*)v4;
  float* hf = xf + 500;
  int tid = threadIdx.x, lane = tid & 63, wid = tid >> 6, blk = blockIdx.x;
  bool worker = blk < 63;
  int u = blk * 8 + wid;

  for (int st = 0; st < TDEC; ++st) {
    unsigned want = (unsigned)(st + 1);
    ull* h0r = (st & 1) ? th0b : th0a;   // tag st   (h0 of st-1 / seed)
    ull* h0w = (st & 1) ? th0a : th0b;   // tag st+1 (h0 of st)
    ull* h1r = (st & 1) ? th1b : th1a;
    ull* h1w = (st & 1) ? th1a : th1b;
    float* lg_w = (st & 1) ? lg1 : lg0;
    const float* lg_r = (st & 1) ? lg0 : lg1;

    if (worker) {
      // ---- A: layer-0 cell ----
      if (tid == 0) {
        ull tv;
        for (;;) {
          tv = gload64(ttok);
          if ((unsigned)(tv >> 32) == want) break;
          __builtin_amdgcn_s_sleep(1);
        }
        sh_tk = (int)(unsigned)tv;
      }
      __syncthreads();
      int tk = sh_tk;
      if (tid >= 64) {
        for (int i = tid - 64; i < 500; i += 448) xf[i] = emb[(size_t)tk * 500 + i];
      } else {
        #pragma unroll
        for (int j = 0; j < 8; ++j) {
          int k = tid + (j << 6);
          if (k < 500) hf[k] = __uint_as_float((unsigned)gload64(&h0r[k]));  // gated
        }
      }
      __syncthreads();
      if (u < 500) cell_unit_tag(u, lane, xf, hf, dWih, dWhh, dbih, dbhh, h0w, want);
      __syncthreads();

      // ---- B: layer-1 cell ----
      if (tid >= 64) {
        for (int i = tid - 64; i < 500; i += 448)
          hf[i] = __uint_as_float((unsigned)gload64(&h1r[i]));               // gated
      }
      poll_tags<500>(h0w, want, xf, tid);
      if (u < 500) cell_unit_tag(u, lane, xf, hf,
          dWih + 750000, dWhh + 750000, dbih + 1500, dbhh + 1500, h1w, want);
      __syncthreads();

      // ---- C: attention scores (blocks 0..31) ----
      if (blk < 32) {
        poll_tags<500>(h1w, want, hfull, tid);
        int s = blk * 8 + wid;
        const float* row = enc_out + (size_t)s * 500;
        float acc = 0.f;
        #pragma unroll
        for (int j = 0; j < 8; ++j) {
          int k = lane + 64 * j;
          if (k < 500) acc += row[k] * hfull[k];
        }
        acc = wred(acc);
        if (lane == 0) gstore64(&tsc[s], ((ull)want << 32) | (ull)__float_as_uint(acc));
        poll_tags<256>(tsc, want, sc, tid);
      } else {
        poll2_tags(h1w, hfull, tsc, sc, want, tid);
      }

      // ---- D: softmax (local) + ctx (8 cols/block) ----
      {
        float myv = (tid < 256) ? sc[tid] : 0.f;
        if (tid < 256) red[tid] = myv;
        __syncthreads();
        for (int s = 128; s > 0; s >>= 1) {
          if (tid < s) red[tid] = fmaxf(red[tid], red[tid + s]);
          __syncthreads();
        }
        float m = red[0]; __syncthreads();
        float e = 0.f;
        if (tid < 256) { e = expf(myv - m); red[tid] = e; }
        __syncthreads();
        for (int s = 128; s > 0; s >>= 1) {
          if (tid < s) red[tid] += red[tid + s];
          __syncthreads();
        }
        float inv = 1.f / red[0]; __syncthreads();
        if (tid < 256) sc[tid] = e * inv;
        __syncthreads();
        int j = blk * 8 + wid;
        if (j < 500) {
          float acc = 0.f;
          #pragma unroll
          for (int q = 0; q < 4; ++q) {
            int s = lane + 64 * q;
            acc += sc[s] * enc_out[(size_t)s * 500 + j];
          }
          acc = wred(acc);
          if (lane == 0) gstore64(&tctx[j], ((ull)want << 32) | (ull)__float_as_uint(acc));
        }
      }

      // ---- E: cvec (8 rows/block) ----
      if (tid >= 64) for (int i = tid - 64; i < 500; i += 448) xf[i] = hfull[i];
      poll_tags<500>(tctx, want, hf, tid);
      {
        int i = blk * 8 + wid;
        if (i < 500) {
          const float* row = cW + (size_t)i * 1000;
          float acc = 0.f;
          #pragma unroll
          for (int j = 0; j < 16; ++j) {
            int k = lane + 64 * j;
            if (k < 1000) acc += row[k] * xf[k];
          }
          acc = wred(acc);
          if (lane == 0)
            gstore64(&tcvec[i], ((ull)want << 32) | (ull)__float_as_uint(tanhf(acc + cb[i])));
        }
      }
      __syncthreads();
    }

    // ---- F: all 256 blocks — logits rows + online-softmax partials ----
    poll_tags<500>(tcvec, want, xf, tid);
    const float4* c4 = v4;
    {
      int lstart = wid * 25, lend = (wid + 1) * 25; if (lend > VPB) lend = VPB;
      int r0 = blk * VPB + lstart, r1 = blk * VPB + lend; if (r1 > V) r1 = V;
      float m = -1e30f, ssum = 0.f; int ix = V;
      for (int rb = r0; rb < r1; rb += 4) {
        int nr = r1 - rb; if (nr > 4) nr = 4;
        float a[4] = {0.f, 0.f, 0.f, 0.f};
        #pragma unroll
        for (int q = 0; q < 2; ++q) {
          int k4 = lane + 64 * q;
          if (k4 < 125) {
            float4 cc = c4[k4];
            #pragma unroll
            for (int rr = 0; rr < 4; ++rr) {
              if (rr < nr) {
                float4 w4 = ((const float4*)(outW + (size_t)(rb + rr) * 500))[k4];
                a[rr] += w4.x * cc.x + w4.y * cc.y + w4.z * cc.z + w4.w * cc.w;
              }
            }
          }
        }
        #pragma unroll
        for (int rr = 0; rr < 4; ++rr) {
          if (rr < nr) {
            float l = wred(a[rr]);
            if (lane == 0) {
              l += outb[rb + rr];
              lg_w[rb + rr] = l;           // block-local plain
              if (l > m) { ssum = ssum * expf(m - l) + 1.f; m = l; ix = rb + rr; }
              else       { ssum += expf(l - m); }
            }
          }
        }
      }
      if (lane == 0) { wm[wid] = m; wsum[wid] = ssum; wix[wid] = ix; }
    }
    __syncthreads();
    if (tid == 0) {
      float M = wm[0], S = wsum[0]; int I = wix[0];
      for (int w2 = 1; w2 < 8; ++w2) {
        if (wm[w2] > M) { S = S * expf(M - wm[w2]) + wsum[w2]; M = wm[w2]; I = wix[w2]; }
        else            { S += wsum[w2] * expf(wm[w2] - M); }
      }
      gstore(&pm[blk], M); gstore(&ps[blk], S);
      __hip_atomic_store(&pix[blk], I, __ATOMIC_RELAXED, __HIP_MEMORY_SCOPE_AGENT);
      __builtin_amdgcn_s_waitcnt(0);       // partials at LLC before the count
      int prev = __hip_atomic_fetch_add(&dcnt[st], 1, __ATOMIC_RELAXED,
                                        __HIP_MEMORY_SCOPE_AGENT);
      lastf = (prev == NDB - 1) ? 1 : 0;
    }
    __syncthreads();

    // ---- last-done block merges partials -> token, stats; publishes ttok ----
    if (lastf) {
      if (tid < 256) { mm[tid] = gload(&pm[tid]); ms[tid] = gload(&ps[tid]); mi[tid] = gload_i(&pix[tid]); }
      __syncthreads();
      for (int s = 128; s > 0; s >>= 1) {
        if (tid < s) {
          float ma = mm[tid], mb = mm[tid + s];
          float sa = ms[tid], sb = ms[tid + s];
          int ia = mi[tid], ib = mi[tid + s];
          if (mb > ma || (mb == ma && ib < ia)) {
            ms[tid] = sa * expf(ma - mb) + sb; mm[tid] = mb; mi[tid] = ib;
          } else {
            ms[tid] = sa + sb * expf(mb - ma);
          }
        }
        __syncthreads();
      }
      if (tid == 0) {
        out_tokens[st] = (float)mi[0];
        gstore(&stats[2 * st], mm[0]);
        gstore(&stats[2 * st + 1], 1.f / ms[0]);
        __builtin_amdgcn_s_waitcnt(0);     // stats at LLC before tok publish
        gstore64(ttok, ((ull)(unsigned)(st + 2) << 32) | (ull)(unsigned)mi[0]);
      }
    }

    // ---- all blocks: probs of step st-1 (own rows; gated via this step's F) ----
    if (st > 0) {
      float mM = gload(&stats[2 * (st - 1)]), iS = gload(&stats[2 * (st - 1) + 1]);
      int base = blk * VPB;
      for (int r = tid; r < VPB; r += 512) {
        int v = base + r;
        if (v < V) out_probs[(size_t)(st - 1) * V + v] = expf(lg_r[v] - mM) * iS;
      }
    }
    __syncthreads();
  }
}

// ---------------- wide probs write for the final step ----------------
__global__ __launch_bounds__(256) void probs_k(const float* __restrict__ logits,
    const float* __restrict__ stats, float* __restrict__ out_probs) {
  int v = blockIdx.x * 256 + threadIdx.x;
  if (v < V) out_probs[v] = expf(logits[v] - stats[0]) * stats[1];
}

extern "C" void kernel_launch(void* const* d_in, const int* in_sizes, int n_in,
                              void* d_out, int out_size, void* d_ws, size_t ws_size,
                              hipStream_t stream) {
  const int*   seq   = (const int*)d_in[0];
  const float* emb   = (const float*)d_in[3];
  const float* e0f_Wih = (const float*)d_in[4];
  const float* e0f_Whh = (const float*)d_in[5];
  const float* e0f_bih = (const float*)d_in[6];
  const float* e0f_bhh = (const float*)d_in[7];
  const float* e0b_Wih = (const float*)d_in[8];
  const float* e0b_Whh = (const float*)d_in[9];
  const float* e0b_bih = (const float*)d_in[10];
  const float* e0b_bhh = (const float*)d_in[11];
  const float* e1f_Wih = (const float*)d_in[12];
  const float* e1f_Whh = (const float*)d_in[13];
  const float* e1f_bih = (const float*)d_in[14];
  const float* e1f_bhh = (const float*)d_in[15];
  const float* e1b_Wih = (const float*)d_in[16];
  const float* e1b_Whh = (const float*)d_in[17];
  const float* e1b_bih = (const float*)d_in[18];
  const float* e1b_bhh = (const float*)d_in[19];
  const float* dWih = (const float*)d_in[20];
  const float* dWhh = (const float*)d_in[21];
  const float* dbih = (const float*)d_in[22];
  const float* dbhh = (const float*)d_in[23];
  const float* cW   = (const float*)d_in[24];
  const float* cb   = (const float*)d_in[25];
  const float* outW = (const float*)d_in[26];
  const float* outb = (const float*)d_in[27];

  float* w = (float*)d_ws;
  float* ex      = w;                      // 128000
  float* x1      = ex + 128000;            // 256000
  float* gxf     = x1 + 256000;            // 384000
  float* gxb     = gxf + 384000;           // 384000
  float* y1f     = gxb + 384000;           // 128000
  float* y1b     = y1f + 128000;           // 128000
  float* enc_out = y1b + 128000;           // 128000
  float* lg0     = enc_out + 128000;       // 50432
  float* lg1     = lg0 + 50432;            // 50432
  float* pm      = lg1 + 50432;            // 256
  float* ps      = pm + 256;               // 256
  float* stats   = ps + 256;               // 192 (2 per step)
  int*   pix     = (int*)(stats + 192);    // 256 ints
  int*   dcnt    = pix + 256;              // 64 ints
  ull*   htag    = (ull*)(dcnt + 64);      // scan tags: 4096 ull (8B-aligned)
  ull* tL0F_A = htag;        ull* tL0F_B = htag + 512;
  ull* tL0B_A = htag + 1024; ull* tL0B_B = htag + 1536;
  ull* tL1F_A = htag + 2048; ull* tL1F_B = htag + 2560;
  ull* tL1B_A = htag + 3072; ull* tL1B_B = htag + 3584;
  ull*   dtag    = htag + 4096;            // decoder tags: 3392 ull
  ull* th0a  = dtag;        ull* th0b = dtag + 512;
  ull* th1a  = dtag + 1024; ull* th1b = dtag + 1536;
  ull* tsc   = dtag + 2048; ull* tctx = dtag + 2304;
  ull* tcvec = dtag + 2816; ull* ttok = dtag + 3328;

  float* outf = (float*)d_out;

  // zero dcnt + all tag buffers (d_ws is re-poisoned before every call)
  hipMemsetAsync(dcnt, 0, 64 * sizeof(int) + 7488 * sizeof(ull), stream);

  init_k<<<1, 64, 0, stream>>>(ttok);
  embed_k<<<SEQ, 128, 0, stream>>>(seq, emb, ex);

  // encoder layer 0
  gemm_nt<<<dim3(24, 4), 256, 0, stream>>>(ex, e0f_Wih, e0f_bih, gxf, SEQ, H3, H);
  gemm_nt<<<dim3(24, 4), 256, 0, stream>>>(ex, e0b_Wih, e0b_bih, gxb, SEQ, H3, H);
  gru_scan_tag<<<2 * SB, 512, 0, stream>>>(gxf, gxb, e0f_Whh, e0b_Whh,
      e0f_bhh, e0b_bhh, tL0F_A, tL0F_B, tL0B_A, tL0B_B, x1, x1 + 500, 1000);

  // encoder layer 1
  gemm_nt<<<dim3(24, 4), 256, 0, stream>>>(x1, e1f_Wih, e1f_bih, gxf, SEQ, H3, 2 * H);
  gemm_nt<<<dim3(24, 4), 256, 0, stream>>>(x1, e1b_Wih, e1b_bih, gxb, SEQ, H3, 2 * H);
  gru_scan_tag<<<2 * SB, 512, 0, stream>>>(gxf, gxb, e1f_Whh, e1b_Whh,
      e1f_bhh, e1b_bhh, tL1F_A, tL1F_B, tL1B_A, tL1B_B, y1f, y1b, 500);
  add_k<<<(SEQ * H + 255) / 256, 256, 0, stream>>>(y1f, y1b, enc_out, SEQ * H);

  // seed decoder h tags (layer-0 final states live in the A buffers, tag 256)
  seed_k<<<1, 512, 0, stream>>>(tL0F_A, tL0B_A, th0a, th1a);

  // persistent decoder: ONE launch for all 64 steps
  dec_persist<<<NDB, 512, 0, stream>>>(emb,
      dWih, dWhh, dbih, dbhh, enc_out, cW, cb, outW, outb,
      th0a, th0b, th1a, th1b, tsc, tctx, tcvec, ttok,
      lg0, lg1, pm, ps, pix, stats, outf, outf + TDEC, dcnt);

  probs_k<<<NLT, 256, 0, stream>>>(((TDEC - 1) & 1) ? lg1 : lg0,
      stats + 2 * (TDEC - 1), outf + TDEC + (size_t)(TDEC - 1) * V);
}